// Round 7
// baseline (264.478 us; speedup 1.0000x reference)
//
#include <hip/hip_runtime.h>

typedef __attribute__((ext_vector_type(8))) short short8v;
typedef __attribute__((ext_vector_type(4))) float f32x4;

#define INVLN2 1.4426950408889634f

__device__ __forceinline__ ushort f2bf(float f) {
  union { float f; unsigned int u; } c; c.f = f;
  return (ushort)((c.u + 0x7FFFu + ((c.u >> 16) & 1u)) >> 16);
}

__device__ __forceinline__ unsigned cvtpk(float a, float b) {
  unsigned r;
  asm("v_cvt_pk_bf16_f32 %0, %1, %2" : "=v"(r) : "v"(a), "v"(b));
  return r;
}

__device__ __forceinline__ float exp2w(float x) {
#if __has_builtin(__builtin_amdgcn_exp2f)
  return __builtin_amdgcn_exp2f(x);
#else
  return __expf(x * 0.6931471805599453f);
#endif
}

__device__ __forceinline__ short8v bits8(unsigned a, unsigned b, unsigned c, unsigned d) {
  union { unsigned u[4]; short8v s; } cv;
  cv.u[0] = a; cv.u[1] = b; cv.u[2] = c; cv.u[3] = d;
  return cv.s;
}

// ---- setup: bf16 weights (q rows pre-scaled by qs*INVLN2), scaled qkv bias,
// gathered rel-pos bias (*INVLN2)
__global__ __launch_bounds__(256) void setup_k(
    const float* __restrict__ qkv_w, const float* __restrict__ proj_w,
    const float* __restrict__ bias_table, const int* __restrict__ rel_idx,
    const float* __restrict__ qkv_b,
    ushort* __restrict__ qkv_wb, ushort* __restrict__ proj_wb,
    float* __restrict__ bias_comb, float* __restrict__ qkv_bs) {
  const float qs = 0.17677669529663687f * INVLN2;  // 1/sqrt(32) * 1/ln2
  int idx = blockIdx.x * 256 + threadIdx.x;
  if (idx < 27648) {                       // 288*96 (rows 0..95 = q)
    qkv_wb[idx] = f2bf(qkv_w[idx] * (idx < 9216 ? qs : 1.0f));
  } else if (idx < 36864) {                // + 96*96
    int i = idx - 27648;
    proj_wb[i] = f2bf(proj_w[i]);
  } else if (idx < 49152) {                // + 3*64*64
    int i = idx - 36864;
    int h = i / 4096, rc = i % 4096;
    bias_comb[i] = bias_table[rel_idx[rc] * 3 + h] * INVLN2;
  } else if (idx < 49440) {                // + 288 scaled qkv bias
    int i = idx - 49152;
    qkv_bs[i] = qkv_b[i] * (i < 96 ? qs : 1.0f);
  }
}

// ---- main fused kernel: IDENTICAL to round 6 (reference for the ablation)
__global__ __launch_bounds__(256, 3) void winattn(
    const float* __restrict__ x, const float* __restrict__ mask,
    const ushort* __restrict__ qkv_wb, const ushort* __restrict__ proj_wb,
    const float* __restrict__ bias_comb, const float* __restrict__ qkv_bs,
    const float* __restrict__ proj_b, float* __restrict__ out) {
  __shared__ ushort klds[2][64][104];  // k row-major [token][chan] (write-once)
  __shared__ ushort vts[2][96][64];    // v^T [chan][token], XOR-swizzled (write-once)

  const int bb = blockIdx.x;           // 0..4095
  const int t = threadIdx.x;
  const int w = t >> 6;
  const int lane = t & 63;
  const int l15 = lane & 15;
  const int g = lane >> 4;
  const int qrow = w * 16 + l15;       // this lane's q-token (all phases)

  const bool ghi = (g >= 2);
  const int srcA = l15 + 16 * ((g & 1) * 2);
  const int srcB = srcA + 16;

  // phase A: x A-fragments for both windows (rows w*16+l15)
  short8v xa[2][3];
  #pragma unroll
  for (int u = 0; u < 2; ++u) {
    const float* xr = x + ((size_t)(bb + u * 4096) * 64 + qrow) * 96 + g * 8;
    #pragma unroll
    for (int ks3 = 0; ks3 < 3; ++ks3) {
      float4 a0 = *reinterpret_cast<const float4*>(xr + ks3 * 32);
      float4 a1 = *reinterpret_cast<const float4*>(xr + ks3 * 32 + 4);
      xa[u][ks3] = bits8(cvtpk(a0.x, a0.y), cvtpk(a0.z, a0.w),
                         cvtpk(a1.x, a1.y), cvtpk(a1.z, a1.w));
    }
  }

  // phase B1: q (swapped mfma -> token-local D), packed into registers
  unsigned qpk[2][6][2];
  #pragma unroll
  for (int nt = 0; nt < 6; ++nt) {
    short8v bf[3];
    #pragma unroll
    for (int ks3 = 0; ks3 < 3; ++ks3)
      bf[ks3] = *reinterpret_cast<const short8v*>(qkv_wb + (nt * 16 + l15) * 96 + ks3 * 32 + g * 8);
    float4 qb = *reinterpret_cast<const float4*>(qkv_bs + nt * 16 + g * 4);
    #pragma unroll
    for (int u = 0; u < 2; ++u) {
      f32x4 acc = {0.f, 0.f, 0.f, 0.f};
      #pragma unroll
      for (int ks3 = 0; ks3 < 3; ++ks3)
        acc = __builtin_amdgcn_mfma_f32_16x16x32_bf16(bf[ks3], xa[u][ks3], acc, 0, 0, 0);
      qpk[u][nt][0] = cvtpk(acc[0] + qb.x, acc[1] + qb.y);
      qpk[u][nt][1] = cvtpk(acc[2] + qb.z, acc[3] + qb.w);
    }
  }
  // q redistribution to QK^T B-fragments (register-only shfl, no LDS)
  short8v qf[2][3];
  #pragma unroll
  for (int u = 0; u < 2; ++u)
    #pragma unroll
    for (int h = 0; h < 3; ++h) {
      unsigned dm[4];
      #pragma unroll
      for (int m = 0; m < 4; ++m) {
        const int sl = (m < 2) ? srcA : srcB;
        unsigned lo = __shfl(qpk[u][2 * h + 0][m & 1], sl);
        unsigned hi = __shfl(qpk[u][2 * h + 1][m & 1], sl);
        dm[m] = ghi ? hi : lo;
      }
      qf[u][h] = bits8(dm[0], dm[1], dm[2], dm[3]);
    }

  // phase B2: k (swapped) -> klds rows w*16+l15 (write-once, own rows)
  #pragma unroll
  for (int nt = 6; nt < 12; ++nt) {
    short8v bf[3];
    #pragma unroll
    for (int ks3 = 0; ks3 < 3; ++ks3)
      bf[ks3] = *reinterpret_cast<const short8v*>(qkv_wb + (nt * 16 + l15) * 96 + ks3 * 32 + g * 8);
    float4 qb = *reinterpret_cast<const float4*>(qkv_bs + nt * 16 + g * 4);
    #pragma unroll
    for (int u = 0; u < 2; ++u) {
      f32x4 acc = {0.f, 0.f, 0.f, 0.f};
      #pragma unroll
      for (int ks3 = 0; ks3 < 3; ++ks3)
        acc = __builtin_amdgcn_mfma_f32_16x16x32_bf16(bf[ks3], xa[u][ks3], acc, 0, 0, 0);
      uint2 pk = make_uint2(cvtpk(acc[0] + qb.x, acc[1] + qb.y),
                            cvtpk(acc[2] + qb.z, acc[3] + qb.w));
      *reinterpret_cast<uint2*>(&klds[u][qrow][(nt - 6) * 16 + g * 4]) = pk;
    }
  }

  // phase B3: v (normal orientation -> [chan][token], XOR-swizzled b64 writes)
  #pragma unroll
  for (int nt = 12; nt < 18; ++nt) {
    const int cw = nt * 16 + l15;
    const int vc = cw - 192;                       // v-chan 0..95
    const int tk = (w * 16 + g * 4) ^ ((vc & 7) << 3);
    short8v bf[3];
    #pragma unroll
    for (int ks3 = 0; ks3 < 3; ++ks3)
      bf[ks3] = *reinterpret_cast<const short8v*>(qkv_wb + cw * 96 + ks3 * 32 + g * 8);
    const float vb = qkv_bs[cw];
    #pragma unroll
    for (int u = 0; u < 2; ++u) {
      f32x4 acc = {0.f, 0.f, 0.f, 0.f};
      #pragma unroll
      for (int ks3 = 0; ks3 < 3; ++ks3)
        acc = __builtin_amdgcn_mfma_f32_16x16x32_bf16(xa[u][ks3], bf[ks3], acc, 0, 0, 0);
      uint2 pk = make_uint2(cvtpk(acc[0] + vb, acc[1] + vb),
                            cvtpk(acc[2] + vb, acc[3] + vb));
      *reinterpret_cast<uint2*>(&vts[u][vc][tk]) = pk;
    }
  }

  // preload shift mask (shared by both windows & all heads), *INVLN2
  const float* mrow = mask + (size_t)bb * 4096 + qrow * 64;
  float mk[4][4];
  #pragma unroll
  for (int tj = 0; tj < 4; ++tj) {
    float4 m4 = *reinterpret_cast<const float4*>(mrow + tj * 16 + g * 4);
    mk[tj][0] = m4.x * INVLN2; mk[tj][1] = m4.y * INVLN2;
    mk[tj][2] = m4.z * INVLN2; mk[tj][3] = m4.w * INVLN2;
  }

  __syncthreads();   // publish klds + vts (the only barrier)

  const float* bcb0 = bias_comb + qrow * 64;
  short8v ofv[3][2];   // per-head normalized O A-fragments, stashed for proj

  #pragma unroll
  for (int h = 0; h < 3; ++h) {
    // QK^T swapped: lane holds S[q=qrow][k=tj*16+g*4+r] (in exp2 domain)
    f32x4 s[2][4];
    #pragma unroll
    for (int tj = 0; tj < 4; ++tj) {
      #pragma unroll
      for (int u = 0; u < 2; ++u) {
        short8v kf = *reinterpret_cast<const short8v*>(&klds[u][tj * 16 + l15][h * 32 + g * 8]);
        f32x4 z = {0.f, 0.f, 0.f, 0.f};
        s[u][tj] = __builtin_amdgcn_mfma_f32_16x16x32_bf16(kf, qf[u][h], z, 0, 0, 0);
      }
    }
    // + (rel-pos bias + mask) [both pre-scaled by 1/ln2]; exp2; row-sum
    #pragma unroll
    for (int tj = 0; tj < 4; ++tj) {
      float4 bc4 = *reinterpret_cast<const float4*>(bcb0 + h * 4096 + tj * 16 + g * 4);
      float bm[4] = {bc4.x + mk[tj][0], bc4.y + mk[tj][1],
                     bc4.z + mk[tj][2], bc4.w + mk[tj][3]};
      #pragma unroll
      for (int u = 0; u < 2; ++u)
        #pragma unroll
        for (int r = 0; r < 4; ++r) s[u][tj][r] += bm[r];
    }
    float inv[2];
    #pragma unroll
    for (int u = 0; u < 2; ++u) {
      #pragma unroll
      for (int tj = 0; tj < 4; ++tj)
        #pragma unroll
        for (int r = 0; r < 4; ++r) s[u][tj][r] = exp2w(s[u][tj][r]);
      float sm = ((s[u][0][0] + s[u][0][1]) + (s[u][0][2] + s[u][0][3]))
               + ((s[u][1][0] + s[u][1][1]) + (s[u][1][2] + s[u][1][3]))
               + ((s[u][2][0] + s[u][2][1]) + (s[u][2][2] + s[u][2][3]))
               + ((s[u][3][0] + s[u][3][1]) + (s[u][3][2] + s[u][3][3]));
      sm += __shfl_xor(sm, 16);
      sm += __shfl_xor(sm, 32);
      inv[u] = __builtin_amdgcn_rcpf(sm);
    }
    // pack P pairs, redistribute to PV B-fragments (register-only shfl)
    unsigned ppk[2][4][2];
    #pragma unroll
    for (int u = 0; u < 2; ++u)
      #pragma unroll
      for (int tj = 0; tj < 4; ++tj) {
        ppk[u][tj][0] = cvtpk(s[u][tj][0], s[u][tj][1]);
        ppk[u][tj][1] = cvtpk(s[u][tj][2], s[u][tj][3]);
      }
    short8v pfv[2][2];
    #pragma unroll
    for (int u = 0; u < 2; ++u)
      #pragma unroll
      for (int ks2 = 0; ks2 < 2; ++ks2) {
        unsigned dm[4];
        #pragma unroll
        for (int m = 0; m < 4; ++m) {
          const int sl = (m < 2) ? srcA : srcB;
          unsigned lo = __shfl(ppk[u][ks2 * 2 + 0][m & 1], sl);
          unsigned hi = __shfl(ppk[u][ks2 * 2 + 1][m & 1], sl);
          dm[m] = ghi ? hi : lo;
        }
        pfv[u][ks2] = bits8(dm[0], dm[1], dm[2], dm[3]);
      }
    // PV swapped: O[q=qrow][d], lane-local q again (swizzled vts reads)
    f32x4 oacc[2][2];
    #pragma unroll
    for (int u = 0; u < 2; ++u)
      #pragma unroll
      for (int nt = 0; nt < 2; ++nt) {
        const int vc = h * 32 + nt * 16 + l15;
        f32x4 o = {0.f, 0.f, 0.f, 0.f};
        #pragma unroll
        for (int ks2 = 0; ks2 < 2; ++ks2) {
          const int tk = (ks2 * 32 + g * 8) ^ ((vc & 7) << 3);
          short8v vf = *reinterpret_cast<const short8v*>(&vts[u][vc][tk]);
          o = __builtin_amdgcn_mfma_f32_16x16x32_bf16(vf, pfv[u][ks2], o, 0, 0, 0);
        }
        oacc[u][nt] = o;
      }
    // normalize+pack O, redistribute to proj A-fragments; stash for proj
    #pragma unroll
    for (int u = 0; u < 2; ++u) {
      unsigned opk[2][2];
      #pragma unroll
      for (int nt = 0; nt < 2; ++nt) {
        opk[nt][0] = cvtpk(oacc[u][nt][0] * inv[u], oacc[u][nt][1] * inv[u]);
        opk[nt][1] = cvtpk(oacc[u][nt][2] * inv[u], oacc[u][nt][3] * inv[u]);
      }
      unsigned dm[4];
      #pragma unroll
      for (int m = 0; m < 4; ++m) {
        const int sl = (m < 2) ? srcA : srcB;
        unsigned lo = __shfl(opk[0][m & 1], sl);
        unsigned hi = __shfl(opk[1][m & 1], sl);
        dm[m] = ghi ? hi : lo;
      }
      ofv[h][u] = bits8(dm[0], dm[1], dm[2], dm[3]);
    }
  }

  // output projection (all heads): pacc[u][nt2] = sum_h O_h @ Wp_h
  f32x4 pacc[2][6];
  #pragma unroll
  for (int u = 0; u < 2; ++u)
    #pragma unroll
    for (int nt2 = 0; nt2 < 6; ++nt2) pacc[u][nt2] = (f32x4){0.f, 0.f, 0.f, 0.f};
  #pragma unroll
  for (int h = 0; h < 3; ++h) {
    #pragma unroll
    for (int nt2 = 0; nt2 < 6; ++nt2) {
      short8v pfw = *reinterpret_cast<const short8v*>(proj_wb + (nt2 * 16 + l15) * 96 + h * 32 + g * 8);
      #pragma unroll
      for (int u = 0; u < 2; ++u)
        pacc[u][nt2] = __builtin_amdgcn_mfma_f32_16x16x32_bf16(ofv[h][u], pfw, pacc[u][nt2], 0, 0, 0);
    }
  }

  // epilogue: + proj bias, f32 stores for both windows
  float pb[6];
  #pragma unroll
  for (int nt2 = 0; nt2 < 6; ++nt2) pb[nt2] = proj_b[nt2 * 16 + l15];
  #pragma unroll
  for (int u = 0; u < 2; ++u) {
    float* ob = out + (size_t)(bb + u * 4096) * 6144 + (w * 16 + g * 4) * 96 + l15;
    #pragma unroll
    for (int nt2 = 0; nt2 < 6; ++nt2)
      #pragma unroll
      for (int r = 0; r < 4; ++r)
        ob[r * 96 + nt2 * 16] = pacc[u][nt2][r] + pb[nt2];
  }
}

// ---- ABLATION PROBE: exactly the pre-barrier half of winattn (x load, QKV
// GEMM, q shfl-redistribution, k/v LDS publish, mask preload, barrier), with
// checksum sinks to defeat DCE (rule #17). Writes only to d_ws scratch.
__global__ __launch_bounds__(256, 3) void probe_qkv(
    const float* __restrict__ x, const float* __restrict__ mask,
    const ushort* __restrict__ qkv_wb, const float* __restrict__ qkv_bs,
    float* __restrict__ sink) {
  __shared__ ushort klds[2][64][104];
  __shared__ ushort vts[2][96][64];

  const int bb = blockIdx.x;
  const int t = threadIdx.x;
  const int w = t >> 6;
  const int lane = t & 63;
  const int l15 = lane & 15;
  const int g = lane >> 4;
  const int qrow = w * 16 + l15;

  const bool ghi = (g >= 2);
  const int srcA = l15 + 16 * ((g & 1) * 2);
  const int srcB = srcA + 16;

  short8v xa[2][3];
  #pragma unroll
  for (int u = 0; u < 2; ++u) {
    const float* xr = x + ((size_t)(bb + u * 4096) * 64 + qrow) * 96 + g * 8;
    #pragma unroll
    for (int ks3 = 0; ks3 < 3; ++ks3) {
      float4 a0 = *reinterpret_cast<const float4*>(xr + ks3 * 32);
      float4 a1 = *reinterpret_cast<const float4*>(xr + ks3 * 32 + 4);
      xa[u][ks3] = bits8(cvtpk(a0.x, a0.y), cvtpk(a0.z, a0.w),
                         cvtpk(a1.x, a1.y), cvtpk(a1.z, a1.w));
    }
  }

  unsigned qpk[2][6][2];
  #pragma unroll
  for (int nt = 0; nt < 6; ++nt) {
    short8v bf[3];
    #pragma unroll
    for (int ks3 = 0; ks3 < 3; ++ks3)
      bf[ks3] = *reinterpret_cast<const short8v*>(qkv_wb + (nt * 16 + l15) * 96 + ks3 * 32 + g * 8);
    float4 qb = *reinterpret_cast<const float4*>(qkv_bs + nt * 16 + g * 4);
    #pragma unroll
    for (int u = 0; u < 2; ++u) {
      f32x4 acc = {0.f, 0.f, 0.f, 0.f};
      #pragma unroll
      for (int ks3 = 0; ks3 < 3; ++ks3)
        acc = __builtin_amdgcn_mfma_f32_16x16x32_bf16(bf[ks3], xa[u][ks3], acc, 0, 0, 0);
      qpk[u][nt][0] = cvtpk(acc[0] + qb.x, acc[1] + qb.y);
      qpk[u][nt][1] = cvtpk(acc[2] + qb.z, acc[3] + qb.w);
    }
  }
  short8v qf[2][3];
  #pragma unroll
  for (int u = 0; u < 2; ++u)
    #pragma unroll
    for (int h = 0; h < 3; ++h) {
      unsigned dm[4];
      #pragma unroll
      for (int m = 0; m < 4; ++m) {
        const int sl = (m < 2) ? srcA : srcB;
        unsigned lo = __shfl(qpk[u][2 * h + 0][m & 1], sl);
        unsigned hi = __shfl(qpk[u][2 * h + 1][m & 1], sl);
        dm[m] = ghi ? hi : lo;
      }
      qf[u][h] = bits8(dm[0], dm[1], dm[2], dm[3]);
    }

  #pragma unroll
  for (int nt = 6; nt < 12; ++nt) {
    short8v bf[3];
    #pragma unroll
    for (int ks3 = 0; ks3 < 3; ++ks3)
      bf[ks3] = *reinterpret_cast<const short8v*>(qkv_wb + (nt * 16 + l15) * 96 + ks3 * 32 + g * 8);
    float4 qb = *reinterpret_cast<const float4*>(qkv_bs + nt * 16 + g * 4);
    #pragma unroll
    for (int u = 0; u < 2; ++u) {
      f32x4 acc = {0.f, 0.f, 0.f, 0.f};
      #pragma unroll
      for (int ks3 = 0; ks3 < 3; ++ks3)
        acc = __builtin_amdgcn_mfma_f32_16x16x32_bf16(bf[ks3], xa[u][ks3], acc, 0, 0, 0);
      uint2 pk = make_uint2(cvtpk(acc[0] + qb.x, acc[1] + qb.y),
                            cvtpk(acc[2] + qb.z, acc[3] + qb.w));
      *reinterpret_cast<uint2*>(&klds[u][qrow][(nt - 6) * 16 + g * 4]) = pk;
    }
  }

  #pragma unroll
  for (int nt = 12; nt < 18; ++nt) {
    const int cw = nt * 16 + l15;
    const int vc = cw - 192;
    const int tk = (w * 16 + g * 4) ^ ((vc & 7) << 3);
    short8v bf[3];
    #pragma unroll
    for (int ks3 = 0; ks3 < 3; ++ks3)
      bf[ks3] = *reinterpret_cast<const short8v*>(qkv_wb + cw * 96 + ks3 * 32 + g * 8);
    const float vb = qkv_bs[cw];
    #pragma unroll
    for (int u = 0; u < 2; ++u) {
      f32x4 acc = {0.f, 0.f, 0.f, 0.f};
      #pragma unroll
      for (int ks3 = 0; ks3 < 3; ++ks3)
        acc = __builtin_amdgcn_mfma_f32_16x16x32_bf16(xa[u][ks3], bf[ks3], acc, 0, 0, 0);
      uint2 pk = make_uint2(cvtpk(acc[0] + vb, acc[1] + vb),
                            cvtpk(acc[2] + vb, acc[3] + vb));
      *reinterpret_cast<uint2*>(&vts[u][vc][tk]) = pk;
    }
  }

  const float* mrow = mask + (size_t)bb * 4096 + qrow * 64;
  float mk[4][4];
  #pragma unroll
  for (int tj = 0; tj < 4; ++tj) {
    float4 m4 = *reinterpret_cast<const float4*>(mrow + tj * 16 + g * 4);
    mk[tj][0] = m4.x * INVLN2; mk[tj][1] = m4.y * INVLN2;
    mk[tj][2] = m4.z * INVLN2; mk[tj][3] = m4.w * INVLN2;
  }

  __syncthreads();

  // checksum sinks: keep qf, mask regs, and the LDS contents (hence all
  // upstream MFMAs/loads/writes) live.
  float cs = 0.f;
  #pragma unroll
  for (int u = 0; u < 2; ++u)
    #pragma unroll
    for (int h = 0; h < 3; ++h) {
      int4 qi = *reinterpret_cast<const int4*>(&qf[u][h]);
      cs += (float)(qi.x ^ qi.y ^ qi.z ^ qi.w);
    }
  #pragma unroll
  for (int tj = 0; tj < 4; ++tj)
    #pragma unroll
    for (int r = 0; r < 4; ++r) cs += mk[tj][r];
  #pragma unroll
  for (int u = 0; u < 2; ++u) {
    int4 ki = *reinterpret_cast<const int4*>(&klds[u][qrow][g * 8]);
    int4 vi = *reinterpret_cast<const int4*>(&vts[u][t % 96][(t & 7) * 8]);
    cs += (float)(ki.x ^ ki.w) + (float)(vi.x ^ vi.w);
  }
  sink[(size_t)bb * 256 + t] = cs;
}

extern "C" void kernel_launch(void* const* d_in, const int* in_sizes, int n_in,
                              void* d_out, int out_size, void* d_ws, size_t ws_size,
                              hipStream_t stream) {
  const float* x          = (const float*)d_in[0];
  const float* mask       = (const float*)d_in[1];
  const float* qkv_w      = (const float*)d_in[2];
  const float* qkv_b      = (const float*)d_in[3];
  const float* proj_w     = (const float*)d_in[4];
  const float* proj_b     = (const float*)d_in[5];
  const float* bias_table = (const float*)d_in[6];
  const int*   rel_idx    = (const int*)d_in[7];

  char* ws = (char*)d_ws;
  ushort* qkv_wb    = (ushort*)ws;                    // 288*96*2 = 55296 B
  ushort* proj_wb   = (ushort*)(ws + 55296);          // 96*96*2  = 18432 B
  float*  bias_comb = (float*)(ws + 55296 + 18432);   // 3*64*64*4 = 49152 B
  float*  qkv_bs    = (float*)(ws + 55296 + 18432 + 49152);  // 288*4 = 1152 B

  setup_k<<<194, 256, 0, stream>>>(qkv_w, proj_w, bias_table, rel_idx, qkv_b,
                                   qkv_wb, proj_wb, bias_comb, qkv_bs);
  winattn<<<4096, 256, 0, stream>>>(x, mask, qkv_wb, proj_wb,
                                    bias_comb, qkv_bs, proj_b, (float*)d_out);

  // diagnostic probe (scratch-only); its dur = bench_total - winattn - setup
  const size_t probe_off = 131072;
  const size_t probe_bytes = (size_t)4096 * 256 * 4;
  if (ws_size >= probe_off + probe_bytes) {
    probe_qkv<<<4096, 256, 0, stream>>>(x, mask, qkv_wb, qkv_bs,
                                        (float*)(ws + probe_off));
  }
}

// Round 9
// 167.526 us; speedup vs baseline: 1.5787x; 1.5787x over previous
//
#include <hip/hip_runtime.h>

typedef __attribute__((ext_vector_type(8))) short short8v;
typedef __attribute__((ext_vector_type(4))) float f32x4;

#define INVLN2 1.4426950408889634f

__device__ __forceinline__ ushort f2bf(float f) {
  union { float f; unsigned int u; } c; c.f = f;
  return (ushort)((c.u + 0x7FFFu + ((c.u >> 16) & 1u)) >> 16);
}

__device__ __forceinline__ unsigned cvtpk(float a, float b) {
  unsigned r;
  asm("v_cvt_pk_bf16_f32 %0, %1, %2" : "=v"(r) : "v"(a), "v"(b));
  return r;
}

__device__ __forceinline__ float exp2w(float x) {
#if __has_builtin(__builtin_amdgcn_exp2f)
  return __builtin_amdgcn_exp2f(x);
#else
  return __expf(x * 0.6931471805599453f);
#endif
}

__device__ __forceinline__ short8v bits8(unsigned a, unsigned b, unsigned c, unsigned d) {
  union { unsigned u[4]; short8v s; } cv;
  cv.u[0] = a; cv.u[1] = b; cv.u[2] = c; cv.u[3] = d;
  return cv.s;
}

// ---- setup: bf16 weights (q rows pre-scaled by qs*INVLN2), scaled qkv bias,
// gathered rel-pos bias (*INVLN2)
__global__ __launch_bounds__(256) void setup_k(
    const float* __restrict__ qkv_w, const float* __restrict__ proj_w,
    const float* __restrict__ bias_table, const int* __restrict__ rel_idx,
    const float* __restrict__ qkv_b,
    ushort* __restrict__ qkv_wb, ushort* __restrict__ proj_wb,
    float* __restrict__ bias_comb, float* __restrict__ qkv_bs) {
  const float qs = 0.17677669529663687f * INVLN2;  // 1/sqrt(32) * 1/ln2
  int idx = blockIdx.x * 256 + threadIdx.x;
  if (idx < 27648) {                       // 288*96 (rows 0..95 = q)
    qkv_wb[idx] = f2bf(qkv_w[idx] * (idx < 9216 ? qs : 1.0f));
  } else if (idx < 36864) {                // + 96*96
    int i = idx - 27648;
    proj_wb[i] = f2bf(proj_w[i]);
  } else if (idx < 49152) {                // + 3*64*64
    int i = idx - 36864;
    int h = i / 4096, rc = i % 4096;
    bias_comb[i] = bias_table[rel_idx[rc] * 3 + h] * INVLN2;
  } else if (idx < 49440) {                // + 288 scaled qkv bias
    int i = idx - 49152;
    qkv_bs[i] = qkv_b[i] * (i < 96 ? qs : 1.0f);
  }
}

// ---- main fused kernel: one block per window PAIR {bb, bb+4096}.
// All LDS write-once -> barrier -> read-only; cross-lane via shfl (known-good).
// This round: HBM loads issued first, QKV weight loads double-buffered,
// bias+mask fully hoisted out of the head loop, launch_bounds(256,2) for
// VGPR headroom (occupancy 2 vs 3 blocks measured perf-neutral in r4/r6).
__global__ __launch_bounds__(256, 2) void winattn(
    const float* __restrict__ x, const float* __restrict__ mask,
    const ushort* __restrict__ qkv_wb, const ushort* __restrict__ proj_wb,
    const float* __restrict__ bias_comb, const float* __restrict__ qkv_bs,
    const float* __restrict__ proj_b, float* __restrict__ out) {
  __shared__ ushort klds[2][64][104];  // k row-major [token][chan] (write-once)
  __shared__ ushort vts[2][96][64];    // v^T [chan][token], XOR-swizzled (write-once)

  const int bb = blockIdx.x;           // 0..4095
  const int t = threadIdx.x;
  const int w = t >> 6;
  const int lane = t & 63;
  const int l15 = lane & 15;
  const int g = lane >> 4;
  const int qrow = w * 16 + l15;       // this lane's q-token (all phases)

  const bool ghi = (g >= 2);
  const int srcA = l15 + 16 * ((g & 1) * 2);
  const int srcB = srcA + 16;

  // ---- issue ALL HBM-latency loads first: x (12x16B) + mask (4x16B)
  float4 xr4[2][3][2];
  #pragma unroll
  for (int u = 0; u < 2; ++u) {
    const float* xr = x + ((size_t)(bb + u * 4096) * 64 + qrow) * 96 + g * 8;
    #pragma unroll
    for (int ks3 = 0; ks3 < 3; ++ks3) {
      xr4[u][ks3][0] = *reinterpret_cast<const float4*>(xr + ks3 * 32);
      xr4[u][ks3][1] = *reinterpret_cast<const float4*>(xr + ks3 * 32 + 4);
    }
  }
  const float* mrow = mask + (size_t)bb * 4096 + qrow * 64;
  float4 mk4[4];
  #pragma unroll
  for (int tj = 0; tj < 4; ++tj)
    mk4[tj] = *reinterpret_cast<const float4*>(mrow + tj * 16 + g * 4);

  // x -> bf16 A-fragments
  short8v xa[2][3];
  #pragma unroll
  for (int u = 0; u < 2; ++u)
    #pragma unroll
    for (int ks3 = 0; ks3 < 3; ++ks3) {
      const float4 a0 = xr4[u][ks3][0], a1 = xr4[u][ks3][1];
      xa[u][ks3] = bits8(cvtpk(a0.x, a0.y), cvtpk(a0.z, a0.w),
                         cvtpk(a1.x, a1.y), cvtpk(a1.z, a1.w));
    }

  // ---- QKV GEMM, merged nt=0..17 loop with double-buffered weight prefetch.
  // nt 0..5 -> q (swapped mfma, token-local D, packed to regs)
  // nt 6..11 -> k (swapped) into klds; nt 12..17 -> v (normal) into vts
  unsigned qpk[2][6][2];
  short8v bfA[3];
  float4 qbA = {0.f, 0.f, 0.f, 0.f}, qbB;
  float vbA = 0.f, vbB;
  {
    const ushort* wr = qkv_wb + l15 * 96 + g * 8;
    bfA[0] = *reinterpret_cast<const short8v*>(wr);
    bfA[1] = *reinterpret_cast<const short8v*>(wr + 32);
    bfA[2] = *reinterpret_cast<const short8v*>(wr + 64);
    qbA = *reinterpret_cast<const float4*>(qkv_bs + g * 4);
  }
  #pragma unroll
  for (int nt = 0; nt < 18; ++nt) {
    short8v bfB[3];
    if (nt < 17) {   // prefetch next iteration's weights+bias (compile-time)
      const ushort* wr = qkv_wb + ((nt + 1) * 16 + l15) * 96 + g * 8;
      bfB[0] = *reinterpret_cast<const short8v*>(wr);
      bfB[1] = *reinterpret_cast<const short8v*>(wr + 32);
      bfB[2] = *reinterpret_cast<const short8v*>(wr + 64);
      if (nt + 1 < 12) qbB = *reinterpret_cast<const float4*>(qkv_bs + (nt + 1) * 16 + g * 4);
      else             vbB = qkv_bs[(nt + 1) * 16 + l15];
    }
    if (nt < 6) {                       // q
      #pragma unroll
      for (int u = 0; u < 2; ++u) {
        f32x4 acc = {0.f, 0.f, 0.f, 0.f};
        #pragma unroll
        for (int ks3 = 0; ks3 < 3; ++ks3)
          acc = __builtin_amdgcn_mfma_f32_16x16x32_bf16(bfA[ks3], xa[u][ks3], acc, 0, 0, 0);
        qpk[u][nt][0] = cvtpk(acc[0] + qbA.x, acc[1] + qbA.y);
        qpk[u][nt][1] = cvtpk(acc[2] + qbA.z, acc[3] + qbA.w);
      }
    } else if (nt < 12) {               // k
      #pragma unroll
      for (int u = 0; u < 2; ++u) {
        f32x4 acc = {0.f, 0.f, 0.f, 0.f};
        #pragma unroll
        for (int ks3 = 0; ks3 < 3; ++ks3)
          acc = __builtin_amdgcn_mfma_f32_16x16x32_bf16(bfA[ks3], xa[u][ks3], acc, 0, 0, 0);
        uint2 pk = make_uint2(cvtpk(acc[0] + qbA.x, acc[1] + qbA.y),
                              cvtpk(acc[2] + qbA.z, acc[3] + qbA.w));
        *reinterpret_cast<uint2*>(&klds[u][qrow][(nt - 6) * 16 + g * 4]) = pk;
      }
    } else {                            // v
      const int vc = nt * 16 + l15 - 192;            // v-chan 0..95
      const int tk = (w * 16 + g * 4) ^ ((vc & 7) << 3);
      #pragma unroll
      for (int u = 0; u < 2; ++u) {
        f32x4 acc = {0.f, 0.f, 0.f, 0.f};
        #pragma unroll
        for (int ks3 = 0; ks3 < 3; ++ks3)
          acc = __builtin_amdgcn_mfma_f32_16x16x32_bf16(xa[u][ks3], bfA[ks3], acc, 0, 0, 0);
        uint2 pk = make_uint2(cvtpk(acc[0] + vbA, acc[1] + vbA),
                              cvtpk(acc[2] + vbA, acc[3] + vbA));
        *reinterpret_cast<uint2*>(&vts[u][vc][tk]) = pk;
      }
    }
    if (nt < 17) {
      bfA[0] = bfB[0]; bfA[1] = bfB[1]; bfA[2] = bfB[2];
      qbA = qbB; vbA = vbB;
    }
  }

  // q redistribution to QK^T B-fragments (shfl; known-correct r6 pattern)
  short8v qf[2][3];
  #pragma unroll
  for (int u = 0; u < 2; ++u)
    #pragma unroll
    for (int h = 0; h < 3; ++h) {
      unsigned dm[4];
      #pragma unroll
      for (int m = 0; m < 4; ++m) {
        const int sl = (m < 2) ? srcA : srcB;
        unsigned lo = __shfl(qpk[u][2 * h + 0][m & 1], sl);
        unsigned hi = __shfl(qpk[u][2 * h + 1][m & 1], sl);
        dm[m] = ghi ? hi : lo;
      }
      qf[u][h] = bits8(dm[0], dm[1], dm[2], dm[3]);
    }

  // ---- hoist ALL rel-pos bias loads (L2) and fold mask: bmk[h][tj][r]
  const float* bcb0 = bias_comb + qrow * 64;
  float4 bc4[3][4];
  #pragma unroll
  for (int h = 0; h < 3; ++h)
    #pragma unroll
    for (int tj = 0; tj < 4; ++tj)
      bc4[h][tj] = *reinterpret_cast<const float4*>(bcb0 + h * 4096 + tj * 16 + g * 4);
  float bmk[3][4][4];
  #pragma unroll
  for (int h = 0; h < 3; ++h)
    #pragma unroll
    for (int tj = 0; tj < 4; ++tj) {
      bmk[h][tj][0] = bc4[h][tj].x + mk4[tj].x * INVLN2;
      bmk[h][tj][1] = bc4[h][tj].y + mk4[tj].y * INVLN2;
      bmk[h][tj][2] = bc4[h][tj].z + mk4[tj].z * INVLN2;
      bmk[h][tj][3] = bc4[h][tj].w + mk4[tj].w * INVLN2;
    }

  __syncthreads();   // publish klds + vts (the only barrier)

  short8v ofv[3][2];   // per-head normalized O A-fragments, stashed for proj

  #pragma unroll
  for (int h = 0; h < 3; ++h) {
    // QK^T swapped: lane holds S[q=qrow][k=tj*16+g*4+r] (in exp2 domain)
    f32x4 s[2][4];
    #pragma unroll
    for (int tj = 0; tj < 4; ++tj) {
      #pragma unroll
      for (int u = 0; u < 2; ++u) {
        short8v kf = *reinterpret_cast<const short8v*>(&klds[u][tj * 16 + l15][h * 32 + g * 8]);
        f32x4 z = {0.f, 0.f, 0.f, 0.f};
        s[u][tj] = __builtin_amdgcn_mfma_f32_16x16x32_bf16(kf, qf[u][h], z, 0, 0, 0);
      }
    }
    // + (bias+mask) pre-combined in regs; exp2; row-sum
    #pragma unroll
    for (int tj = 0; tj < 4; ++tj)
      #pragma unroll
      for (int u = 0; u < 2; ++u)
        #pragma unroll
        for (int r = 0; r < 4; ++r) s[u][tj][r] += bmk[h][tj][r];
    float inv[2];
    #pragma unroll
    for (int u = 0; u < 2; ++u) {
      #pragma unroll
      for (int tj = 0; tj < 4; ++tj)
        #pragma unroll
        for (int r = 0; r < 4; ++r) s[u][tj][r] = exp2w(s[u][tj][r]);
      float sm = ((s[u][0][0] + s[u][0][1]) + (s[u][0][2] + s[u][0][3]))
               + ((s[u][1][0] + s[u][1][1]) + (s[u][1][2] + s[u][1][3]))
               + ((s[u][2][0] + s[u][2][1]) + (s[u][2][2] + s[u][2][3]))
               + ((s[u][3][0] + s[u][3][1]) + (s[u][3][2] + s[u][3][3]));
      sm += __shfl_xor(sm, 16);
      sm += __shfl_xor(sm, 32);
      inv[u] = __builtin_amdgcn_rcpf(sm);
    }
    // pack P pairs, redistribute to PV B-fragments (shfl)
    unsigned ppk[2][4][2];
    #pragma unroll
    for (int u = 0; u < 2; ++u)
      #pragma unroll
      for (int tj = 0; tj < 4; ++tj) {
        ppk[u][tj][0] = cvtpk(s[u][tj][0], s[u][tj][1]);
        ppk[u][tj][1] = cvtpk(s[u][tj][2], s[u][tj][3]);
      }
    short8v pfv[2][2];
    #pragma unroll
    for (int u = 0; u < 2; ++u)
      #pragma unroll
      for (int ks2 = 0; ks2 < 2; ++ks2) {
        unsigned dm[4];
        #pragma unroll
        for (int m = 0; m < 4; ++m) {
          const int sl = (m < 2) ? srcA : srcB;
          unsigned lo = __shfl(ppk[u][ks2 * 2 + 0][m & 1], sl);
          unsigned hi = __shfl(ppk[u][ks2 * 2 + 1][m & 1], sl);
          dm[m] = ghi ? hi : lo;
        }
        pfv[u][ks2] = bits8(dm[0], dm[1], dm[2], dm[3]);
      }
    // PV swapped: O[q=qrow][d], lane-local q again (swizzled vts reads)
    f32x4 oacc[2][2];
    #pragma unroll
    for (int u = 0; u < 2; ++u)
      #pragma unroll
      for (int nt = 0; nt < 2; ++nt) {
        const int vc = h * 32 + nt * 16 + l15;
        f32x4 o = {0.f, 0.f, 0.f, 0.f};
        #pragma unroll
        for (int ks2 = 0; ks2 < 2; ++ks2) {
          const int tk = (ks2 * 32 + g * 8) ^ ((vc & 7) << 3);
          short8v vf = *reinterpret_cast<const short8v*>(&vts[u][vc][tk]);
          o = __builtin_amdgcn_mfma_f32_16x16x32_bf16(vf, pfv[u][ks2], o, 0, 0, 0);
        }
        oacc[u][nt] = o;
      }
    // normalize+pack O, redistribute to proj A-fragments; stash for proj
    #pragma unroll
    for (int u = 0; u < 2; ++u) {
      unsigned opk[2][2];
      #pragma unroll
      for (int nt = 0; nt < 2; ++nt) {
        opk[nt][0] = cvtpk(oacc[u][nt][0] * inv[u], oacc[u][nt][1] * inv[u]);
        opk[nt][1] = cvtpk(oacc[u][nt][2] * inv[u], oacc[u][nt][3] * inv[u]);
      }
      unsigned dm[4];
      #pragma unroll
      for (int m = 0; m < 4; ++m) {
        const int sl = (m < 2) ? srcA : srcB;
        unsigned lo = __shfl(opk[0][m & 1], sl);
        unsigned hi = __shfl(opk[1][m & 1], sl);
        dm[m] = ghi ? hi : lo;
      }
      ofv[h][u] = bits8(dm[0], dm[1], dm[2], dm[3]);
    }
  }

  // output projection (all heads): pacc[u][nt2] = sum_h O_h @ Wp_h
  f32x4 pacc[2][6];
  #pragma unroll
  for (int u = 0; u < 2; ++u)
    #pragma unroll
    for (int nt2 = 0; nt2 < 6; ++nt2) pacc[u][nt2] = (f32x4){0.f, 0.f, 0.f, 0.f};
  #pragma unroll
  for (int h = 0; h < 3; ++h) {
    #pragma unroll
    for (int nt2 = 0; nt2 < 6; ++nt2) {
      short8v pfw = *reinterpret_cast<const short8v*>(proj_wb + (nt2 * 16 + l15) * 96 + h * 32 + g * 8);
      #pragma unroll
      for (int u = 0; u < 2; ++u)
        pacc[u][nt2] = __builtin_amdgcn_mfma_f32_16x16x32_bf16(ofv[h][u], pfw, pacc[u][nt2], 0, 0, 0);
    }
  }

  // epilogue: + proj bias, f32 stores for both windows
  float pb[6];
  #pragma unroll
  for (int nt2 = 0; nt2 < 6; ++nt2) pb[nt2] = proj_b[nt2 * 16 + l15];
  #pragma unroll
  for (int u = 0; u < 2; ++u) {
    float* ob = out + (size_t)(bb + u * 4096) * 6144 + (w * 16 + g * 4) * 96 + l15;
    #pragma unroll
    for (int nt2 = 0; nt2 < 6; ++nt2)
      #pragma unroll
      for (int r = 0; r < 4; ++r)
        ob[r * 96 + nt2 * 16] = pacc[u][nt2][r] + pb[nt2];
  }
}

extern "C" void kernel_launch(void* const* d_in, const int* in_sizes, int n_in,
                              void* d_out, int out_size, void* d_ws, size_t ws_size,
                              hipStream_t stream) {
  const float* x          = (const float*)d_in[0];
  const float* mask       = (const float*)d_in[1];
  const float* qkv_w      = (const float*)d_in[2];
  const float* qkv_b      = (const float*)d_in[3];
  const float* proj_w     = (const float*)d_in[4];
  const float* proj_b     = (const float*)d_in[5];
  const float* bias_table = (const float*)d_in[6];
  const int*   rel_idx    = (const int*)d_in[7];

  char* ws = (char*)d_ws;
  ushort* qkv_wb    = (ushort*)ws;                    // 288*96*2 = 55296 B
  ushort* proj_wb   = (ushort*)(ws + 55296);          // 96*96*2  = 18432 B
  float*  bias_comb = (float*)(ws + 55296 + 18432);   // 3*64*64*4 = 49152 B
  float*  qkv_bs    = (float*)(ws + 55296 + 18432 + 49152);  // 288*4 = 1152 B

  setup_k<<<194, 256, 0, stream>>>(qkv_w, proj_w, bias_table, rel_idx, qkv_b,
                                   qkv_wb, proj_wb, bias_comb, qkv_bs);
  winattn<<<4096, 256, 0, stream>>>(x, mask, qkv_wb, proj_wb,
                                    bias_comb, qkv_bs, proj_b, (float*)d_out);
}

// Round 12
// 165.058 us; speedup vs baseline: 1.6023x; 1.0149x over previous
//
#include <hip/hip_runtime.h>

typedef __attribute__((ext_vector_type(8))) short short8v;
typedef __attribute__((ext_vector_type(4))) float f32x4;

#define INVLN2 1.4426950408889634f

__device__ __forceinline__ ushort f2bf(float f) {
  union { float f; unsigned int u; } c; c.f = f;
  return (ushort)((c.u + 0x7FFFu + ((c.u >> 16) & 1u)) >> 16);
}

__device__ __forceinline__ unsigned cvtpk(float a, float b) {
  unsigned r;
  asm("v_cvt_pk_bf16_f32 %0, %1, %2" : "=v"(r) : "v"(a), "v"(b));
  return r;
}

__device__ __forceinline__ float exp2w(float x) {
#if __has_builtin(__builtin_amdgcn_exp2f)
  return __builtin_amdgcn_exp2f(x);
#else
  return __expf(x * 0.6931471805599453f);
#endif
}

__device__ __forceinline__ short8v bits8(unsigned a, unsigned b, unsigned c, unsigned d) {
  union { unsigned u[4]; short8v s; } cv;
  cv.u[0] = a; cv.u[1] = b; cv.u[2] = c; cv.u[3] = d;
  return cv.s;
}

// ---- setup: bf16 weights (q rows pre-scaled by qs*INVLN2), scaled qkv bias,
// gathered rel-pos bias (*INVLN2). proj_w columns PRE-PERMUTED by
// kappa(j) = 32h + 16b + 4g + d  (j = 32h + 8g + 4b + d) so the runtime proj
// B-fragment k-order matches the lane-local O k-order (zero-shuffle scheme).
__global__ __launch_bounds__(256) void setup_k(
    const float* __restrict__ qkv_w, const float* __restrict__ proj_w,
    const float* __restrict__ bias_table, const int* __restrict__ rel_idx,
    const float* __restrict__ qkv_b,
    ushort* __restrict__ qkv_wb, ushort* __restrict__ proj_wb,
    float* __restrict__ bias_comb, float* __restrict__ qkv_bs) {
  const float qs = 0.17677669529663687f * INVLN2;  // 1/sqrt(32) * 1/ln2
  int idx = blockIdx.x * 256 + threadIdx.x;
  if (idx < 27648) {                       // 288*96 (rows 0..95 = q)
    qkv_wb[idx] = f2bf(qkv_w[idx] * (idx < 9216 ? qs : 1.0f));
  } else if (idx < 36864) {                // + 96*96, column-permuted by kappa
    int i = idx - 27648;
    int cw = i / 96, j = i % 96;
    int h = j >> 5, kk = j & 31;
    int g = kk >> 3, b = (kk & 4) >> 2, d = kk & 3;
    int src = h * 32 + 16 * b + 4 * g + d;
    proj_wb[i] = f2bf(proj_w[cw * 96 + src]);
  } else if (idx < 49152) {                // + 3*64*64
    int i = idx - 36864;
    int h = i / 4096, rc = i % 4096;
    bias_comb[i] = bias_table[rel_idx[rc] * 3 + h] * INVLN2;
  } else if (idx < 49440) {                // + 288 scaled qkv bias
    int i = idx - 49152;
    qkv_bs[i] = qkv_b[i] * (i < 96 ? qs : 1.0f);
  }
}

// ---- main fused kernel: one block per window PAIR {bb, bb+4096}.
// r9 structure (known-good), but ZERO-SHUFFLE fragment handling: K and V are
// written to LDS at permuted k-slots (sigma: chan 16m+4g+r -> slot
// 32*(m>>1)+8g+4*(m&1)+r; token 16w+4g+r -> slot 32*(w>>1)+8g+4*(w&1)+r),
// and proj weights are pre-permuted in setup. q/P/O fragments are then pure
// lane-local register packs — no ds_bpermute anywhere (only 12 shfl_xor
// row-sums remain). All LDS write-once -> barrier -> read-only.
__global__ __launch_bounds__(256, 2) void winattn(
    const float* __restrict__ x, const float* __restrict__ mask,
    const ushort* __restrict__ qkv_wb, const ushort* __restrict__ proj_wb,
    const float* __restrict__ bias_comb, const float* __restrict__ qkv_bs,
    const float* __restrict__ proj_b, float* __restrict__ out) {
  __shared__ ushort klds[2][64][104];  // k [token][chan-slot] (write-once)
  __shared__ ushort vts[2][96][64];    // v^T [chan][token-slot], XOR-swizzled

  const int bb = blockIdx.x;           // 0..4095
  const int t = threadIdx.x;
  const int w = t >> 6;
  const int lane = t & 63;
  const int l15 = lane & 15;
  const int g = lane >> 4;
  const int qrow = w * 16 + l15;       // this lane's q-token (all phases)

  // ---- issue ALL HBM-latency loads first: x (12x16B) + mask (4x16B)
  float4 xr4[2][3][2];
  #pragma unroll
  for (int u = 0; u < 2; ++u) {
    const float* xr = x + ((size_t)(bb + u * 4096) * 64 + qrow) * 96 + g * 8;
    #pragma unroll
    for (int ks3 = 0; ks3 < 3; ++ks3) {
      xr4[u][ks3][0] = *reinterpret_cast<const float4*>(xr + ks3 * 32);
      xr4[u][ks3][1] = *reinterpret_cast<const float4*>(xr + ks3 * 32 + 4);
    }
  }
  const float* mrow = mask + (size_t)bb * 4096 + qrow * 64;
  float4 mk4[4];
  #pragma unroll
  for (int tj = 0; tj < 4; ++tj)
    mk4[tj] = *reinterpret_cast<const float4*>(mrow + tj * 16 + g * 4);

  // x -> bf16 A-fragments
  short8v xa[2][3];
  #pragma unroll
  for (int u = 0; u < 2; ++u)
    #pragma unroll
    for (int ks3 = 0; ks3 < 3; ++ks3) {
      const float4 a0 = xr4[u][ks3][0], a1 = xr4[u][ks3][1];
      xa[u][ks3] = bits8(cvtpk(a0.x, a0.y), cvtpk(a0.z, a0.w),
                         cvtpk(a1.x, a1.y), cvtpk(a1.z, a1.w));
    }

  // ---- QKV GEMM, merged nt=0..17 loop, 1-ahead weight prefetch (r9 style).
  unsigned qpk[2][6][2];
  short8v bfA[3];
  float4 qbA = {0.f, 0.f, 0.f, 0.f}, qbB;
  float vbA = 0.f, vbB;
  {
    const ushort* wr = qkv_wb + l15 * 96 + g * 8;
    bfA[0] = *reinterpret_cast<const short8v*>(wr);
    bfA[1] = *reinterpret_cast<const short8v*>(wr + 32);
    bfA[2] = *reinterpret_cast<const short8v*>(wr + 64);
    qbA = *reinterpret_cast<const float4*>(qkv_bs + g * 4);
  }
  #pragma unroll
  for (int nt = 0; nt < 18; ++nt) {
    short8v bfB[3];
    if (nt < 17) {   // prefetch next iteration's weights+bias
      const ushort* wr = qkv_wb + ((nt + 1) * 16 + l15) * 96 + g * 8;
      bfB[0] = *reinterpret_cast<const short8v*>(wr);
      bfB[1] = *reinterpret_cast<const short8v*>(wr + 32);
      bfB[2] = *reinterpret_cast<const short8v*>(wr + 64);
      if (nt + 1 < 12) qbB = *reinterpret_cast<const float4*>(qkv_bs + (nt + 1) * 16 + g * 4);
      else             vbB = qkv_bs[(nt + 1) * 16 + l15];
    }
    if (nt < 6) {                       // q (swapped mfma -> token-local D)
      #pragma unroll
      for (int u = 0; u < 2; ++u) {
        f32x4 acc = {0.f, 0.f, 0.f, 0.f};
        #pragma unroll
        for (int ks3 = 0; ks3 < 3; ++ks3)
          acc = __builtin_amdgcn_mfma_f32_16x16x32_bf16(bfA[ks3], xa[u][ks3], acc, 0, 0, 0);
        qpk[u][nt][0] = cvtpk(acc[0] + qbA.x, acc[1] + qbA.y);
        qpk[u][nt][1] = cvtpk(acc[2] + qbA.z, acc[3] + qbA.w);
      }
    } else if (nt < 12) {               // k (swapped) -> klds, PERMUTED slot
      const int m = nt - 6;
      const int kcol = 32 * (m >> 1) + 8 * g + 4 * (m & 1);  // sigma base
      #pragma unroll
      for (int u = 0; u < 2; ++u) {
        f32x4 acc = {0.f, 0.f, 0.f, 0.f};
        #pragma unroll
        for (int ks3 = 0; ks3 < 3; ++ks3)
          acc = __builtin_amdgcn_mfma_f32_16x16x32_bf16(bfA[ks3], xa[u][ks3], acc, 0, 0, 0);
        uint2 pk = make_uint2(cvtpk(acc[0] + qbA.x, acc[1] + qbA.y),
                              cvtpk(acc[2] + qbA.z, acc[3] + qbA.w));
        *reinterpret_cast<uint2*>(&klds[u][qrow][kcol]) = pk;
      }
    } else {                            // v -> vts, PERMUTED token slot + XOR
      const int vc = nt * 16 + l15 - 192;
      const int tk = (32 * (w >> 1) + 8 * g + 4 * (w & 1)) ^ ((vc & 7) << 3);
      #pragma unroll
      for (int u = 0; u < 2; ++u) {
        f32x4 acc = {0.f, 0.f, 0.f, 0.f};
        #pragma unroll
        for (int ks3 = 0; ks3 < 3; ++ks3)
          acc = __builtin_amdgcn_mfma_f32_16x16x32_bf16(xa[u][ks3], bfA[ks3], acc, 0, 0, 0);
        uint2 pk = make_uint2(cvtpk(acc[0] + vbA, acc[1] + vbA),
                              cvtpk(acc[2] + vbA, acc[3] + vbA));
        *reinterpret_cast<uint2*>(&vts[u][vc][tk]) = pk;
      }
    }
    if (nt < 17) {
      bfA[0] = bfB[0]; bfA[1] = bfB[1]; bfA[2] = bfB[2];
      qbA = qbB; vbA = vbB;
    }
  }

  // q -> QK^T B-fragments: pure lane-local pack (k-order matches klds slots)
  short8v qf[2][3];
  #pragma unroll
  for (int u = 0; u < 2; ++u)
    #pragma unroll
    for (int h = 0; h < 3; ++h)
      qf[u][h] = bits8(qpk[u][2 * h][0], qpk[u][2 * h][1],
                       qpk[u][2 * h + 1][0], qpk[u][2 * h + 1][1]);

  // ---- hoist rel-pos bias loads (L2), fold mask: bmk[h][tj][r]
  const float* bcb0 = bias_comb + qrow * 64;
  float4 bc4[3][4];
  #pragma unroll
  for (int h = 0; h < 3; ++h)
    #pragma unroll
    for (int tj = 0; tj < 4; ++tj)
      bc4[h][tj] = *reinterpret_cast<const float4*>(bcb0 + h * 4096 + tj * 16 + g * 4);
  float bmk[3][4][4];
  #pragma unroll
  for (int h = 0; h < 3; ++h)
    #pragma unroll
    for (int tj = 0; tj < 4; ++tj) {
      bmk[h][tj][0] = bc4[h][tj].x + mk4[tj].x * INVLN2;
      bmk[h][tj][1] = bc4[h][tj].y + mk4[tj].y * INVLN2;
      bmk[h][tj][2] = bc4[h][tj].z + mk4[tj].z * INVLN2;
      bmk[h][tj][3] = bc4[h][tj].w + mk4[tj].w * INVLN2;
    }

  __syncthreads();   // publish klds + vts (the only barrier)

  short8v ofv[3][2];   // per-head normalized O A-fragments (lane-local pack)

  #pragma unroll
  for (int h = 0; h < 3; ++h) {
    // QK^T swapped: lane holds S[q=qrow][k=tj*16+g*4+r] (in exp2 domain)
    f32x4 s[2][4];
    #pragma unroll
    for (int tj = 0; tj < 4; ++tj) {
      #pragma unroll
      for (int u = 0; u < 2; ++u) {
        short8v kf = *reinterpret_cast<const short8v*>(&klds[u][tj * 16 + l15][h * 32 + g * 8]);
        f32x4 z = {0.f, 0.f, 0.f, 0.f};
        s[u][tj] = __builtin_amdgcn_mfma_f32_16x16x32_bf16(kf, qf[u][h], z, 0, 0, 0);
      }
    }
    // + (bias+mask) pre-combined in regs; exp2; row-sum
    #pragma unroll
    for (int tj = 0; tj < 4; ++tj)
      #pragma unroll
      for (int u = 0; u < 2; ++u)
        #pragma unroll
        for (int r = 0; r < 4; ++r) s[u][tj][r] += bmk[h][tj][r];
    float inv[2];
    #pragma unroll
    for (int u = 0; u < 2; ++u) {
      #pragma unroll
      for (int tj = 0; tj < 4; ++tj)
        #pragma unroll
        for (int r = 0; r < 4; ++r) s[u][tj][r] = exp2w(s[u][tj][r]);
      float sm = ((s[u][0][0] + s[u][0][1]) + (s[u][0][2] + s[u][0][3]))
               + ((s[u][1][0] + s[u][1][1]) + (s[u][1][2] + s[u][1][3]))
               + ((s[u][2][0] + s[u][2][1]) + (s[u][2][2] + s[u][2][3]))
               + ((s[u][3][0] + s[u][3][1]) + (s[u][3][2] + s[u][3][3]));
      sm += __shfl_xor(sm, 16);
      sm += __shfl_xor(sm, 32);
      inv[u] = __builtin_amdgcn_rcpf(sm);
    }
    // P -> PV B-fragments: pure lane-local pack (token order = vts slots)
    unsigned ppk[2][4][2];
    #pragma unroll
    for (int u = 0; u < 2; ++u)
      #pragma unroll
      for (int tj = 0; tj < 4; ++tj) {
        ppk[u][tj][0] = cvtpk(s[u][tj][0], s[u][tj][1]);
        ppk[u][tj][1] = cvtpk(s[u][tj][2], s[u][tj][3]);
      }
    short8v pfv[2][2];
    #pragma unroll
    for (int u = 0; u < 2; ++u)
      #pragma unroll
      for (int ks2 = 0; ks2 < 2; ++ks2)
        pfv[u][ks2] = bits8(ppk[u][2 * ks2][0], ppk[u][2 * ks2][1],
                            ppk[u][2 * ks2 + 1][0], ppk[u][2 * ks2 + 1][1]);
    // PV swapped: O[q=qrow][d] (swizzled vts reads; same read code as r9)
    f32x4 oacc[2][2];
    #pragma unroll
    for (int u = 0; u < 2; ++u)
      #pragma unroll
      for (int nt = 0; nt < 2; ++nt) {
        const int vc = h * 32 + nt * 16 + l15;
        f32x4 o = {0.f, 0.f, 0.f, 0.f};
        #pragma unroll
        for (int ks2 = 0; ks2 < 2; ++ks2) {
          const int tk = (ks2 * 32 + g * 8) ^ ((vc & 7) << 3);
          short8v vf = *reinterpret_cast<const short8v*>(&vts[u][vc][tk]);
          o = __builtin_amdgcn_mfma_f32_16x16x32_bf16(vf, pfv[u][ks2], o, 0, 0, 0);
        }
        oacc[u][nt] = o;
      }
    // normalize+pack O -> proj A-fragments: lane-local (proj_wb pre-permuted)
    #pragma unroll
    for (int u = 0; u < 2; ++u) {
      unsigned o00 = cvtpk(oacc[u][0][0] * inv[u], oacc[u][0][1] * inv[u]);
      unsigned o01 = cvtpk(oacc[u][0][2] * inv[u], oacc[u][0][3] * inv[u]);
      unsigned o10 = cvtpk(oacc[u][1][0] * inv[u], oacc[u][1][1] * inv[u]);
      unsigned o11 = cvtpk(oacc[u][1][2] * inv[u], oacc[u][1][3] * inv[u]);
      ofv[h][u] = bits8(o00, o01, o10, o11);
    }
  }

  // output projection (all heads): pacc[u][nt2] = sum_h O_h @ Wp_h
  f32x4 pacc[2][6];
  #pragma unroll
  for (int u = 0; u < 2; ++u)
    #pragma unroll
    for (int nt2 = 0; nt2 < 6; ++nt2) pacc[u][nt2] = (f32x4){0.f, 0.f, 0.f, 0.f};
  #pragma unroll
  for (int h = 0; h < 3; ++h) {
    #pragma unroll
    for (int nt2 = 0; nt2 < 6; ++nt2) {
      short8v pfw = *reinterpret_cast<const short8v*>(proj_wb + (nt2 * 16 + l15) * 96 + h * 32 + g * 8);
      #pragma unroll
      for (int u = 0; u < 2; ++u)
        pacc[u][nt2] = __builtin_amdgcn_mfma_f32_16x16x32_bf16(ofv[h][u], pfw, pacc[u][nt2], 0, 0, 0);
    }
  }

  // epilogue: + proj bias, f32 stores for both windows
  float pb[6];
  #pragma unroll
  for (int nt2 = 0; nt2 < 6; ++nt2) pb[nt2] = proj_b[nt2 * 16 + l15];
  #pragma unroll
  for (int u = 0; u < 2; ++u) {
    float* ob = out + (size_t)(bb + u * 4096) * 6144 + (w * 16 + g * 4) * 96 + l15;
    #pragma unroll
    for (int nt2 = 0; nt2 < 6; ++nt2)
      #pragma unroll
      for (int r = 0; r < 4; ++r)
        ob[r * 96 + nt2 * 16] = pacc[u][nt2][r] + pb[nt2];
  }
}

extern "C" void kernel_launch(void* const* d_in, const int* in_sizes, int n_in,
                              void* d_out, int out_size, void* d_ws, size_t ws_size,
                              hipStream_t stream) {
  const float* x          = (const float*)d_in[0];
  const float* mask       = (const float*)d_in[1];
  const float* qkv_w      = (const float*)d_in[2];
  const float* qkv_b      = (const float*)d_in[3];
  const float* proj_w     = (const float*)d_in[4];
  const float* proj_b     = (const float*)d_in[5];
  const float* bias_table = (const float*)d_in[6];
  const int*   rel_idx    = (const int*)d_in[7];

  char* ws = (char*)d_ws;
  ushort* qkv_wb    = (ushort*)ws;                    // 288*96*2 = 55296 B
  ushort* proj_wb   = (ushort*)(ws + 55296);          // 96*96*2  = 18432 B
  float*  bias_comb = (float*)(ws + 55296 + 18432);   // 3*64*64*4 = 49152 B
  float*  qkv_bs    = (float*)(ws + 55296 + 18432 + 49152);  // 288*4 = 1152 B

  setup_k<<<194, 256, 0, stream>>>(qkv_w, proj_w, bias_table, rel_idx, qkv_b,
                                   qkv_wb, proj_wb, bias_comb, qkv_bs);
  winattn<<<4096, 256, 0, stream>>>(x, mask, qkv_wb, proj_wb,
                                    bias_comb, qkv_bs, proj_b, (float*)d_out);
}

// Round 13
// 162.227 us; speedup vs baseline: 1.6303x; 1.0175x over previous
//
#include <hip/hip_runtime.h>

typedef __attribute__((ext_vector_type(8))) short short8v;
typedef __attribute__((ext_vector_type(4))) float f32x4;

#define INVLN2 1.4426950408889634f

__device__ __forceinline__ ushort f2bf(float f) {
  union { float f; unsigned int u; } c; c.f = f;
  return (ushort)((c.u + 0x7FFFu + ((c.u >> 16) & 1u)) >> 16);
}

__device__ __forceinline__ unsigned cvtpk(float a, float b) {
  unsigned r;
  asm("v_cvt_pk_bf16_f32 %0, %1, %2" : "=v"(r) : "v"(a), "v"(b));
  return r;
}

__device__ __forceinline__ float exp2w(float x) {
#if __has_builtin(__builtin_amdgcn_exp2f)
  return __builtin_amdgcn_exp2f(x);
#else
  return __expf(x * 0.6931471805599453f);
#endif
}

__device__ __forceinline__ short8v bits8(unsigned a, unsigned b, unsigned c, unsigned d) {
  union { unsigned u[4]; short8v s; } cv;
  cv.u[0] = a; cv.u[1] = b; cv.u[2] = c; cv.u[3] = d;
  return cv.s;
}

// ---- setup: bf16 weights (q rows pre-scaled by qs*INVLN2), scaled qkv bias,
// gathered rel-pos bias (*INVLN2). proj_w columns PRE-PERMUTED by
// kappa(j) = 32h + 16b + 4g + d so the runtime proj B-fragment k-order
// matches the lane-local O k-order (zero-shuffle scheme, verified r12).
__global__ __launch_bounds__(256) void setup_k(
    const float* __restrict__ qkv_w, const float* __restrict__ proj_w,
    const float* __restrict__ bias_table, const int* __restrict__ rel_idx,
    const float* __restrict__ qkv_b,
    ushort* __restrict__ qkv_wb, ushort* __restrict__ proj_wb,
    float* __restrict__ bias_comb, float* __restrict__ qkv_bs) {
  const float qs = 0.17677669529663687f * INVLN2;  // 1/sqrt(32) * 1/ln2
  int idx = blockIdx.x * 256 + threadIdx.x;
  if (idx < 27648) {                       // 288*96 (rows 0..95 = q)
    qkv_wb[idx] = f2bf(qkv_w[idx] * (idx < 9216 ? qs : 1.0f));
  } else if (idx < 36864) {                // + 96*96, column-permuted by kappa
    int i = idx - 27648;
    int cw = i / 96, j = i % 96;
    int h = j >> 5, kk = j & 31;
    int g = kk >> 3, b = (kk & 4) >> 2, d = kk & 3;
    int src = h * 32 + 16 * b + 4 * g + d;
    proj_wb[i] = f2bf(proj_w[cw * 96 + src]);
  } else if (idx < 49152) {                // + 3*64*64
    int i = idx - 36864;
    int h = i / 4096, rc = i % 4096;
    bias_comb[i] = bias_table[rel_idx[rc] * 3 + h] * INVLN2;
  } else if (idx < 49440) {                // + 288 scaled qkv bias
    int i = idx - 49152;
    qkv_bs[i] = qkv_b[i] * (i < 96 ? qs : 1.0f);
  }
}

// ---- main fused kernel: FOUR windows per block {bb, bb+4096, bb+2048,
// bb+6144} (u=0..3; pairs {0,1} and {2,3} share a mask row). r12 structure
// (zero-shuffle, known-good) with the u-loop widened 2->4: 4 independent
// MFMA/VALU streams per wave amortize the fixed latency chain.
// LDS = 4*(13312 + 12288) = 102400 B -> 1 block/CU, VGPR budget 512/wave.
__global__ __launch_bounds__(256, 1) void winattn(
    const float* __restrict__ x, const float* __restrict__ mask,
    const ushort* __restrict__ qkv_wb, const ushort* __restrict__ proj_wb,
    const float* __restrict__ bias_comb, const float* __restrict__ qkv_bs,
    const float* __restrict__ proj_b, float* __restrict__ out) {
  __shared__ ushort klds[4][64][104];  // k [token][chan-slot] (write-once)
  __shared__ ushort vts[4][96][64];    // v^T [chan][token-slot], XOR-swizzled

  const int bb = blockIdx.x;           // 0..2047
  const int t = threadIdx.x;
  const int w = t >> 6;
  const int lane = t & 63;
  const int l15 = lane & 15;
  const int g = lane >> 4;
  const int qrow = w * 16 + l15;       // this lane's q-token (all phases)

  // window id per stream u: bb + (u>>1)*2048 + (u&1)*4096
  // mask row per pair p=u>>1: bb + p*2048

  // ---- issue ALL HBM-latency loads first: x (24x16B) + mask (8x16B)
  float4 xr4[4][3][2];
  #pragma unroll
  for (int u = 0; u < 4; ++u) {
    const int win = bb + ((u >> 1) << 11) + ((u & 1) << 12);
    const float* xr = x + ((size_t)win * 64 + qrow) * 96 + g * 8;
    #pragma unroll
    for (int ks3 = 0; ks3 < 3; ++ks3) {
      xr4[u][ks3][0] = *reinterpret_cast<const float4*>(xr + ks3 * 32);
      xr4[u][ks3][1] = *reinterpret_cast<const float4*>(xr + ks3 * 32 + 4);
    }
  }
  float4 mk4[2][4];
  #pragma unroll
  for (int p = 0; p < 2; ++p) {
    const float* mrow = mask + (size_t)(bb + (p << 11)) * 4096 + qrow * 64;
    #pragma unroll
    for (int tj = 0; tj < 4; ++tj)
      mk4[p][tj] = *reinterpret_cast<const float4*>(mrow + tj * 16 + g * 4);
  }

  // x -> bf16 A-fragments
  short8v xa[4][3];
  #pragma unroll
  for (int u = 0; u < 4; ++u)
    #pragma unroll
    for (int ks3 = 0; ks3 < 3; ++ks3) {
      const float4 a0 = xr4[u][ks3][0], a1 = xr4[u][ks3][1];
      xa[u][ks3] = bits8(cvtpk(a0.x, a0.y), cvtpk(a0.z, a0.w),
                         cvtpk(a1.x, a1.y), cvtpk(a1.z, a1.w));
    }

  // ---- QKV GEMM, merged nt=0..17 loop, 1-ahead weight prefetch.
  unsigned qpk[4][6][2];
  short8v bfA[3];
  float4 qbA = {0.f, 0.f, 0.f, 0.f}, qbB;
  float vbA = 0.f, vbB;
  {
    const ushort* wr = qkv_wb + l15 * 96 + g * 8;
    bfA[0] = *reinterpret_cast<const short8v*>(wr);
    bfA[1] = *reinterpret_cast<const short8v*>(wr + 32);
    bfA[2] = *reinterpret_cast<const short8v*>(wr + 64);
    qbA = *reinterpret_cast<const float4*>(qkv_bs + g * 4);
  }
  #pragma unroll
  for (int nt = 0; nt < 18; ++nt) {
    short8v bfB[3];
    if (nt < 17) {   // prefetch next iteration's weights+bias
      const ushort* wr = qkv_wb + ((nt + 1) * 16 + l15) * 96 + g * 8;
      bfB[0] = *reinterpret_cast<const short8v*>(wr);
      bfB[1] = *reinterpret_cast<const short8v*>(wr + 32);
      bfB[2] = *reinterpret_cast<const short8v*>(wr + 64);
      if (nt + 1 < 12) qbB = *reinterpret_cast<const float4*>(qkv_bs + (nt + 1) * 16 + g * 4);
      else             vbB = qkv_bs[(nt + 1) * 16 + l15];
    }
    if (nt < 6) {                       // q (swapped mfma -> token-local D)
      #pragma unroll
      for (int u = 0; u < 4; ++u) {
        f32x4 acc = {0.f, 0.f, 0.f, 0.f};
        #pragma unroll
        for (int ks3 = 0; ks3 < 3; ++ks3)
          acc = __builtin_amdgcn_mfma_f32_16x16x32_bf16(bfA[ks3], xa[u][ks3], acc, 0, 0, 0);
        qpk[u][nt][0] = cvtpk(acc[0] + qbA.x, acc[1] + qbA.y);
        qpk[u][nt][1] = cvtpk(acc[2] + qbA.z, acc[3] + qbA.w);
      }
    } else if (nt < 12) {               // k (swapped) -> klds, permuted slot
      const int m = nt - 6;
      const int kcol = 32 * (m >> 1) + 8 * g + 4 * (m & 1);  // sigma base
      #pragma unroll
      for (int u = 0; u < 4; ++u) {
        f32x4 acc = {0.f, 0.f, 0.f, 0.f};
        #pragma unroll
        for (int ks3 = 0; ks3 < 3; ++ks3)
          acc = __builtin_amdgcn_mfma_f32_16x16x32_bf16(bfA[ks3], xa[u][ks3], acc, 0, 0, 0);
        uint2 pk = make_uint2(cvtpk(acc[0] + qbA.x, acc[1] + qbA.y),
                              cvtpk(acc[2] + qbA.z, acc[3] + qbA.w));
        *reinterpret_cast<uint2*>(&klds[u][qrow][kcol]) = pk;
      }
    } else {                            // v -> vts, permuted token slot + XOR
      const int vc = nt * 16 + l15 - 192;
      const int tk = (32 * (w >> 1) + 8 * g + 4 * (w & 1)) ^ ((vc & 7) << 3);
      #pragma unroll
      for (int u = 0; u < 4; ++u) {
        f32x4 acc = {0.f, 0.f, 0.f, 0.f};
        #pragma unroll
        for (int ks3 = 0; ks3 < 3; ++ks3)
          acc = __builtin_amdgcn_mfma_f32_16x16x32_bf16(xa[u][ks3], bfA[ks3], acc, 0, 0, 0);
        uint2 pk = make_uint2(cvtpk(acc[0] + vbA, acc[1] + vbA),
                              cvtpk(acc[2] + vbA, acc[3] + vbA));
        *reinterpret_cast<uint2*>(&vts[u][vc][tk]) = pk;
      }
    }
    if (nt < 17) {
      bfA[0] = bfB[0]; bfA[1] = bfB[1]; bfA[2] = bfB[2];
      qbA = qbB; vbA = vbB;
    }
  }

  // q -> QK^T B-fragments: pure lane-local pack (zero-shuffle)
  short8v qf[4][3];
  #pragma unroll
  for (int u = 0; u < 4; ++u)
    #pragma unroll
    for (int h = 0; h < 3; ++h)
      qf[u][h] = bits8(qpk[u][2 * h][0], qpk[u][2 * h][1],
                       qpk[u][2 * h + 1][0], qpk[u][2 * h + 1][1]);

  // ---- hoist rel-pos bias loads (L2): bcf[h][tj][r] (shared by all u);
  // mask kept per-pair in mk4, combined per-head below.
  const float* bcb0 = bias_comb + qrow * 64;
  float bcf[3][4][4];
  #pragma unroll
  for (int h = 0; h < 3; ++h)
    #pragma unroll
    for (int tj = 0; tj < 4; ++tj) {
      float4 b4 = *reinterpret_cast<const float4*>(bcb0 + h * 4096 + tj * 16 + g * 4);
      bcf[h][tj][0] = b4.x; bcf[h][tj][1] = b4.y;
      bcf[h][tj][2] = b4.z; bcf[h][tj][3] = b4.w;
    }
  float mkp[2][4][4];
  #pragma unroll
  for (int p = 0; p < 2; ++p)
    #pragma unroll
    for (int tj = 0; tj < 4; ++tj) {
      mkp[p][tj][0] = mk4[p][tj].x * INVLN2;
      mkp[p][tj][1] = mk4[p][tj].y * INVLN2;
      mkp[p][tj][2] = mk4[p][tj].z * INVLN2;
      mkp[p][tj][3] = mk4[p][tj].w * INVLN2;
    }

  __syncthreads();   // publish klds + vts (the only barrier)

  short8v ofv[3][4];   // per-head normalized O A-fragments (lane-local pack)

  #pragma unroll
  for (int h = 0; h < 3; ++h) {
    // QK^T swapped: lane holds S[q=qrow][k=tj*16+g*4+r] (in exp2 domain)
    f32x4 s[4][4];
    #pragma unroll
    for (int tj = 0; tj < 4; ++tj) {
      #pragma unroll
      for (int u = 0; u < 4; ++u) {
        short8v kf = *reinterpret_cast<const short8v*>(&klds[u][tj * 16 + l15][h * 32 + g * 8]);
        f32x4 z = {0.f, 0.f, 0.f, 0.f};
        s[u][tj] = __builtin_amdgcn_mfma_f32_16x16x32_bf16(kf, qf[u][h], z, 0, 0, 0);
      }
    }
    // + (bias + mask) [exp2 domain]; exp2; row-sum
    #pragma unroll
    for (int tj = 0; tj < 4; ++tj)
      #pragma unroll
      for (int r = 0; r < 4; ++r) {
        const float b0 = bcf[h][tj][r] + mkp[0][tj][r];
        const float b1 = bcf[h][tj][r] + mkp[1][tj][r];
        s[0][tj][r] += b0; s[1][tj][r] += b0;
        s[2][tj][r] += b1; s[3][tj][r] += b1;
      }
    float inv[4];
    #pragma unroll
    for (int u = 0; u < 4; ++u) {
      #pragma unroll
      for (int tj = 0; tj < 4; ++tj)
        #pragma unroll
        for (int r = 0; r < 4; ++r) s[u][tj][r] = exp2w(s[u][tj][r]);
      float sm = ((s[u][0][0] + s[u][0][1]) + (s[u][0][2] + s[u][0][3]))
               + ((s[u][1][0] + s[u][1][1]) + (s[u][1][2] + s[u][1][3]))
               + ((s[u][2][0] + s[u][2][1]) + (s[u][2][2] + s[u][2][3]))
               + ((s[u][3][0] + s[u][3][1]) + (s[u][3][2] + s[u][3][3]));
      sm += __shfl_xor(sm, 16);
      sm += __shfl_xor(sm, 32);
      inv[u] = __builtin_amdgcn_rcpf(sm);
    }
    // P -> PV B-fragments: pure lane-local pack (token order = vts slots)
    short8v pfv[4][2];
    #pragma unroll
    for (int u = 0; u < 4; ++u) {
      unsigned p00 = cvtpk(s[u][0][0], s[u][0][1]);
      unsigned p01 = cvtpk(s[u][0][2], s[u][0][3]);
      unsigned p10 = cvtpk(s[u][1][0], s[u][1][1]);
      unsigned p11 = cvtpk(s[u][1][2], s[u][1][3]);
      unsigned p20 = cvtpk(s[u][2][0], s[u][2][1]);
      unsigned p21 = cvtpk(s[u][2][2], s[u][2][3]);
      unsigned p30 = cvtpk(s[u][3][0], s[u][3][1]);
      unsigned p31 = cvtpk(s[u][3][2], s[u][3][3]);
      pfv[u][0] = bits8(p00, p01, p10, p11);
      pfv[u][1] = bits8(p20, p21, p30, p31);
    }
    // PV swapped: O[q=qrow][d] (swizzled vts reads)
    #pragma unroll
    for (int u = 0; u < 4; ++u) {
      f32x4 oacc[2];
      #pragma unroll
      for (int nt = 0; nt < 2; ++nt) {
        const int vc = h * 32 + nt * 16 + l15;
        f32x4 o = {0.f, 0.f, 0.f, 0.f};
        #pragma unroll
        for (int ks2 = 0; ks2 < 2; ++ks2) {
          const int tk = (ks2 * 32 + g * 8) ^ ((vc & 7) << 3);
          short8v vf = *reinterpret_cast<const short8v*>(&vts[u][vc][tk]);
          o = __builtin_amdgcn_mfma_f32_16x16x32_bf16(vf, pfv[u][ks2], o, 0, 0, 0);
        }
        oacc[nt] = o;
      }
      // normalize+pack O -> proj A-fragment (proj_wb pre-permuted)
      unsigned o00 = cvtpk(oacc[0][0] * inv[u], oacc[0][1] * inv[u]);
      unsigned o01 = cvtpk(oacc[0][2] * inv[u], oacc[0][3] * inv[u]);
      unsigned o10 = cvtpk(oacc[1][0] * inv[u], oacc[1][1] * inv[u]);
      unsigned o11 = cvtpk(oacc[1][2] * inv[u], oacc[1][3] * inv[u]);
      ofv[h][u] = bits8(o00, o01, o10, o11);
    }
  }

  // output projection (all heads): pacc[u][nt2] = sum_h O_h @ Wp_h
  f32x4 pacc[4][6];
  #pragma unroll
  for (int u = 0; u < 4; ++u)
    #pragma unroll
    for (int nt2 = 0; nt2 < 6; ++nt2) pacc[u][nt2] = (f32x4){0.f, 0.f, 0.f, 0.f};
  #pragma unroll
  for (int h = 0; h < 3; ++h) {
    #pragma unroll
    for (int nt2 = 0; nt2 < 6; ++nt2) {
      short8v pfw = *reinterpret_cast<const short8v*>(proj_wb + (nt2 * 16 + l15) * 96 + h * 32 + g * 8);
      #pragma unroll
      for (int u = 0; u < 4; ++u)
        pacc[u][nt2] = __builtin_amdgcn_mfma_f32_16x16x32_bf16(ofv[h][u], pfw, pacc[u][nt2], 0, 0, 0);
    }
  }

  // epilogue: + proj bias, f32 stores for all four windows
  float pb[6];
  #pragma unroll
  for (int nt2 = 0; nt2 < 6; ++nt2) pb[nt2] = proj_b[nt2 * 16 + l15];
  #pragma unroll
  for (int u = 0; u < 4; ++u) {
    const int win = bb + ((u >> 1) << 11) + ((u & 1) << 12);
    float* ob = out + (size_t)win * 6144 + (w * 16 + g * 4) * 96 + l15;
    #pragma unroll
    for (int nt2 = 0; nt2 < 6; ++nt2)
      #pragma unroll
      for (int r = 0; r < 4; ++r)
        ob[r * 96 + nt2 * 16] = pacc[u][nt2][r] + pb[nt2];
  }
}

extern "C" void kernel_launch(void* const* d_in, const int* in_sizes, int n_in,
                              void* d_out, int out_size, void* d_ws, size_t ws_size,
                              hipStream_t stream) {
  const float* x          = (const float*)d_in[0];
  const float* mask       = (const float*)d_in[1];
  const float* qkv_w      = (const float*)d_in[2];
  const float* qkv_b      = (const float*)d_in[3];
  const float* proj_w     = (const float*)d_in[4];
  const float* proj_b     = (const float*)d_in[5];
  const float* bias_table = (const float*)d_in[6];
  const int*   rel_idx    = (const int*)d_in[7];

  char* ws = (char*)d_ws;
  ushort* qkv_wb    = (ushort*)ws;                    // 288*96*2 = 55296 B
  ushort* proj_wb   = (ushort*)(ws + 55296);          // 96*96*2  = 18432 B
  float*  bias_comb = (float*)(ws + 55296 + 18432);   // 3*64*64*4 = 49152 B
  float*  qkv_bs    = (float*)(ws + 55296 + 18432 + 49152);  // 288*4 = 1152 B

  setup_k<<<194, 256, 0, stream>>>(qkv_w, proj_w, bias_table, rel_idx, qkv_b,
                                   qkv_wb, proj_wb, bias_comb, qkv_bs);
  winattn<<<2048, 256, 0, stream>>>(x, mask, qkv_wb, proj_wb,
                                    bias_comb, qkv_bs, proj_b, (float*)d_out);
}

// Round 14
// 161.338 us; speedup vs baseline: 1.6393x; 1.0055x over previous
//
#include <hip/hip_runtime.h>

typedef __attribute__((ext_vector_type(8))) short short8v;
typedef __attribute__((ext_vector_type(4))) float f32x4;

#define INVLN2 1.4426950408889634f

__device__ __forceinline__ ushort f2bf(float f) {
  union { float f; unsigned int u; } c; c.f = f;
  return (ushort)((c.u + 0x7FFFu + ((c.u >> 16) & 1u)) >> 16);
}

__device__ __forceinline__ unsigned cvtpk(float a, float b) {
  unsigned r;
  asm("v_cvt_pk_bf16_f32 %0, %1, %2" : "=v"(r) : "v"(a), "v"(b));
  return r;
}

__device__ __forceinline__ float exp2w(float x) {
#if __has_builtin(__builtin_amdgcn_exp2f)
  return __builtin_amdgcn_exp2f(x);
#else
  return __expf(x * 0.6931471805599453f);
#endif
}

__device__ __forceinline__ short8v bits8(unsigned a, unsigned b, unsigned c, unsigned d) {
  union { unsigned u[4]; short8v s; } cv;
  cv.u[0] = a; cv.u[1] = b; cv.u[2] = c; cv.u[3] = d;
  return cv.s;
}

// ---- setup: bf16 weights (q rows pre-scaled by qs*INVLN2), scaled qkv bias,
// gathered rel-pos bias (*INVLN2). proj_w columns PRE-PERMUTED by
// kappa(j) = 32h + 16b + 4g + d so the runtime proj B-fragment k-order
// matches the lane-local O k-order (zero-shuffle scheme, verified r12).
__global__ __launch_bounds__(256) void setup_k(
    const float* __restrict__ qkv_w, const float* __restrict__ proj_w,
    const float* __restrict__ bias_table, const int* __restrict__ rel_idx,
    const float* __restrict__ qkv_b,
    ushort* __restrict__ qkv_wb, ushort* __restrict__ proj_wb,
    float* __restrict__ bias_comb, float* __restrict__ qkv_bs) {
  const float qs = 0.17677669529663687f * INVLN2;  // 1/sqrt(32) * 1/ln2
  int idx = blockIdx.x * 256 + threadIdx.x;
  if (idx < 27648) {                       // 288*96 (rows 0..95 = q)
    qkv_wb[idx] = f2bf(qkv_w[idx] * (idx < 9216 ? qs : 1.0f));
  } else if (idx < 36864) {                // + 96*96, column-permuted by kappa
    int i = idx - 27648;
    int cw = i / 96, j = i % 96;
    int h = j >> 5, kk = j & 31;
    int g = kk >> 3, b = (kk & 4) >> 2, d = kk & 3;
    int src = h * 32 + 16 * b + 4 * g + d;
    proj_wb[i] = f2bf(proj_w[cw * 96 + src]);
  } else if (idx < 49152) {                // + 3*64*64
    int i = idx - 36864;
    int h = i / 4096, rc = i % 4096;
    bias_comb[i] = bias_table[rel_idx[rc] * 3 + h] * INVLN2;
  } else if (idx < 49440) {                // + 288 scaled qkv bias
    int i = idx - 49152;
    qkv_bs[i] = qkv_b[i] * (i < 96 ? qs : 1.0f);
  }
}

// ---- main fused kernel: FOUR windows per block {bb, bb+4096, bb+2048,
// bb+6144} (r13 structure, zero-shuffle, known-good) + qkv weights staged
// into LDS once per block (rows padded 96->104: 2-way bank aliasing = free;
// kills the per-nt L2 weight-latency gating of the QKV loop).
// LDS = 53248 (klds) + 49152 (vts) + 59904 (wq) = 162304 B -> 1 block/CU.
__global__ __launch_bounds__(256, 1) void winattn(
    const float* __restrict__ x, const float* __restrict__ mask,
    const ushort* __restrict__ qkv_wb, const ushort* __restrict__ proj_wb,
    const float* __restrict__ bias_comb, const float* __restrict__ qkv_bs,
    const float* __restrict__ proj_b, float* __restrict__ out) {
  __shared__ ushort klds[4][64][104];  // k [token][chan-slot] (write-once)
  __shared__ ushort vts[4][96][64];    // v^T [chan][token-slot], XOR-swizzled
  __shared__ ushort wq[29952];         // qkv weights [288][104-padded]

  const int bb = blockIdx.x;           // 0..2047
  const int t = threadIdx.x;
  const int w = t >> 6;
  const int lane = t & 63;
  const int l15 = lane & 15;
  const int g = lane >> 4;
  const int qrow = w * 16 + l15;       // this lane's q-token (all phases)

  // ---- issue ALL HBM-latency loads first: x (24x16B) + mask (8x16B)
  float4 xr4[4][3][2];
  #pragma unroll
  for (int u = 0; u < 4; ++u) {
    const int win = bb + ((u >> 1) << 11) + ((u & 1) << 12);
    const float* xr = x + ((size_t)win * 64 + qrow) * 96 + g * 8;
    #pragma unroll
    for (int ks3 = 0; ks3 < 3; ++ks3) {
      xr4[u][ks3][0] = *reinterpret_cast<const float4*>(xr + ks3 * 32);
      xr4[u][ks3][1] = *reinterpret_cast<const float4*>(xr + ks3 * 32 + 4);
    }
  }
  float4 mk4[2][4];
  #pragma unroll
  for (int p = 0; p < 2; ++p) {
    const float* mrow = mask + (size_t)(bb + (p << 11)) * 4096 + qrow * 64;
    #pragma unroll
    for (int tj = 0; tj < 4; ++tj)
      mk4[p][tj] = *reinterpret_cast<const float4*>(mrow + tj * 16 + g * 4);
  }

  // ---- stage qkv weights into LDS (once per block, shared by 4 waves).
  // 288 rows x 12 b128-chunks = 3456 chunks; 256 threads x 13.5 iters.
  #pragma unroll
  for (int i = 0; i < 14; ++i) {
    const int c = i * 256 + t;
    if (i < 13 || t < 128) {
      const int row = c / 12, cc = c % 12;
      short8v wv = *reinterpret_cast<const short8v*>(qkv_wb + row * 96 + cc * 8);
      *reinterpret_cast<short8v*>(&wq[row * 104 + cc * 8]) = wv;
    }
  }
  __syncthreads();   // weights published

  // x -> bf16 A-fragments
  short8v xa[4][3];
  #pragma unroll
  for (int u = 0; u < 4; ++u)
    #pragma unroll
    for (int ks3 = 0; ks3 < 3; ++ks3) {
      const float4 a0 = xr4[u][ks3][0], a1 = xr4[u][ks3][1];
      xa[u][ks3] = bits8(cvtpk(a0.x, a0.y), cvtpk(a0.z, a0.w),
                         cvtpk(a1.x, a1.y), cvtpk(a1.z, a1.w));
    }

  // ---- QKV GEMM, merged nt=0..17 loop, 1-ahead weight prefetch from LDS.
  unsigned qpk[4][6][2];
  short8v bfA[3];
  float4 qbA = {0.f, 0.f, 0.f, 0.f}, qbB;
  float vbA = 0.f, vbB;
  {
    const ushort* wr = &wq[l15 * 104 + g * 8];
    bfA[0] = *reinterpret_cast<const short8v*>(wr);
    bfA[1] = *reinterpret_cast<const short8v*>(wr + 32);
    bfA[2] = *reinterpret_cast<const short8v*>(wr + 64);
    qbA = *reinterpret_cast<const float4*>(qkv_bs + g * 4);
  }
  #pragma unroll
  for (int nt = 0; nt < 18; ++nt) {
    short8v bfB[3];
    if (nt < 17) {   // prefetch next iteration's weights (LDS) + bias (L2)
      const ushort* wr = &wq[((nt + 1) * 16 + l15) * 104 + g * 8];
      bfB[0] = *reinterpret_cast<const short8v*>(wr);
      bfB[1] = *reinterpret_cast<const short8v*>(wr + 32);
      bfB[2] = *reinterpret_cast<const short8v*>(wr + 64);
      if (nt + 1 < 12) qbB = *reinterpret_cast<const float4*>(qkv_bs + (nt + 1) * 16 + g * 4);
      else             vbB = qkv_bs[(nt + 1) * 16 + l15];
    }
    if (nt < 6) {                       // q (swapped mfma -> token-local D)
      #pragma unroll
      for (int u = 0; u < 4; ++u) {
        f32x4 acc = {0.f, 0.f, 0.f, 0.f};
        #pragma unroll
        for (int ks3 = 0; ks3 < 3; ++ks3)
          acc = __builtin_amdgcn_mfma_f32_16x16x32_bf16(bfA[ks3], xa[u][ks3], acc, 0, 0, 0);
        qpk[u][nt][0] = cvtpk(acc[0] + qbA.x, acc[1] + qbA.y);
        qpk[u][nt][1] = cvtpk(acc[2] + qbA.z, acc[3] + qbA.w);
      }
    } else if (nt < 12) {               // k (swapped) -> klds, permuted slot
      const int m = nt - 6;
      const int kcol = 32 * (m >> 1) + 8 * g + 4 * (m & 1);  // sigma base
      #pragma unroll
      for (int u = 0; u < 4; ++u) {
        f32x4 acc = {0.f, 0.f, 0.f, 0.f};
        #pragma unroll
        for (int ks3 = 0; ks3 < 3; ++ks3)
          acc = __builtin_amdgcn_mfma_f32_16x16x32_bf16(bfA[ks3], xa[u][ks3], acc, 0, 0, 0);
        uint2 pk = make_uint2(cvtpk(acc[0] + qbA.x, acc[1] + qbA.y),
                              cvtpk(acc[2] + qbA.z, acc[3] + qbA.w));
        *reinterpret_cast<uint2*>(&klds[u][qrow][kcol]) = pk;
      }
    } else {                            // v -> vts, permuted token slot + XOR
      const int vc = nt * 16 + l15 - 192;
      const int tk = (32 * (w >> 1) + 8 * g + 4 * (w & 1)) ^ ((vc & 7) << 3);
      #pragma unroll
      for (int u = 0; u < 4; ++u) {
        f32x4 acc = {0.f, 0.f, 0.f, 0.f};
        #pragma unroll
        for (int ks3 = 0; ks3 < 3; ++ks3)
          acc = __builtin_amdgcn_mfma_f32_16x16x32_bf16(xa[u][ks3], bfA[ks3], acc, 0, 0, 0);
        uint2 pk = make_uint2(cvtpk(acc[0] + vbA, acc[1] + vbA),
                              cvtpk(acc[2] + vbA, acc[3] + vbA));
        *reinterpret_cast<uint2*>(&vts[u][vc][tk]) = pk;
      }
    }
    if (nt < 17) {
      bfA[0] = bfB[0]; bfA[1] = bfB[1]; bfA[2] = bfB[2];
      qbA = qbB; vbA = vbB;
    }
  }

  // q -> QK^T B-fragments: pure lane-local pack (zero-shuffle)
  short8v qf[4][3];
  #pragma unroll
  for (int u = 0; u < 4; ++u)
    #pragma unroll
    for (int h = 0; h < 3; ++h)
      qf[u][h] = bits8(qpk[u][2 * h][0], qpk[u][2 * h][1],
                       qpk[u][2 * h + 1][0], qpk[u][2 * h + 1][1]);

  // ---- hoist rel-pos bias loads (L2): bcf[h][tj][r] (shared by all u);
  // mask kept per-pair, combined per-head below.
  const float* bcb0 = bias_comb + qrow * 64;
  float bcf[3][4][4];
  #pragma unroll
  for (int h = 0; h < 3; ++h)
    #pragma unroll
    for (int tj = 0; tj < 4; ++tj) {
      float4 b4 = *reinterpret_cast<const float4*>(bcb0 + h * 4096 + tj * 16 + g * 4);
      bcf[h][tj][0] = b4.x; bcf[h][tj][1] = b4.y;
      bcf[h][tj][2] = b4.z; bcf[h][tj][3] = b4.w;
    }
  float mkp[2][4][4];
  #pragma unroll
  for (int p = 0; p < 2; ++p)
    #pragma unroll
    for (int tj = 0; tj < 4; ++tj) {
      mkp[p][tj][0] = mk4[p][tj].x * INVLN2;
      mkp[p][tj][1] = mk4[p][tj].y * INVLN2;
      mkp[p][tj][2] = mk4[p][tj].z * INVLN2;
      mkp[p][tj][3] = mk4[p][tj].w * INVLN2;
    }

  __syncthreads();   // publish klds + vts

  short8v ofv[3][4];   // per-head normalized O A-fragments (lane-local pack)

  #pragma unroll
  for (int h = 0; h < 3; ++h) {
    // QK^T swapped: lane holds S[q=qrow][k=tj*16+g*4+r] (in exp2 domain)
    f32x4 s[4][4];
    #pragma unroll
    for (int tj = 0; tj < 4; ++tj) {
      #pragma unroll
      for (int u = 0; u < 4; ++u) {
        short8v kf = *reinterpret_cast<const short8v*>(&klds[u][tj * 16 + l15][h * 32 + g * 8]);
        f32x4 z = {0.f, 0.f, 0.f, 0.f};
        s[u][tj] = __builtin_amdgcn_mfma_f32_16x16x32_bf16(kf, qf[u][h], z, 0, 0, 0);
      }
    }
    // + (bias + mask) [exp2 domain]; exp2; row-sum
    #pragma unroll
    for (int tj = 0; tj < 4; ++tj)
      #pragma unroll
      for (int r = 0; r < 4; ++r) {
        const float b0 = bcf[h][tj][r] + mkp[0][tj][r];
        const float b1 = bcf[h][tj][r] + mkp[1][tj][r];
        s[0][tj][r] += b0; s[1][tj][r] += b0;
        s[2][tj][r] += b1; s[3][tj][r] += b1;
      }
    float inv[4];
    #pragma unroll
    for (int u = 0; u < 4; ++u) {
      #pragma unroll
      for (int tj = 0; tj < 4; ++tj)
        #pragma unroll
        for (int r = 0; r < 4; ++r) s[u][tj][r] = exp2w(s[u][tj][r]);
      float sm = ((s[u][0][0] + s[u][0][1]) + (s[u][0][2] + s[u][0][3]))
               + ((s[u][1][0] + s[u][1][1]) + (s[u][1][2] + s[u][1][3]))
               + ((s[u][2][0] + s[u][2][1]) + (s[u][2][2] + s[u][2][3]))
               + ((s[u][3][0] + s[u][3][1]) + (s[u][3][2] + s[u][3][3]));
      sm += __shfl_xor(sm, 16);
      sm += __shfl_xor(sm, 32);
      inv[u] = __builtin_amdgcn_rcpf(sm);
    }
    // P -> PV B-fragments: pure lane-local pack (token order = vts slots)
    short8v pfv[4][2];
    #pragma unroll
    for (int u = 0; u < 4; ++u) {
      unsigned p00 = cvtpk(s[u][0][0], s[u][0][1]);
      unsigned p01 = cvtpk(s[u][0][2], s[u][0][3]);
      unsigned p10 = cvtpk(s[u][1][0], s[u][1][1]);
      unsigned p11 = cvtpk(s[u][1][2], s[u][1][3]);
      unsigned p20 = cvtpk(s[u][2][0], s[u][2][1]);
      unsigned p21 = cvtpk(s[u][2][2], s[u][2][3]);
      unsigned p30 = cvtpk(s[u][3][0], s[u][3][1]);
      unsigned p31 = cvtpk(s[u][3][2], s[u][3][3]);
      pfv[u][0] = bits8(p00, p01, p10, p11);
      pfv[u][1] = bits8(p20, p21, p30, p31);
    }
    // PV swapped: O[q=qrow][d] (swizzled vts reads)
    #pragma unroll
    for (int u = 0; u < 4; ++u) {
      f32x4 oacc[2];
      #pragma unroll
      for (int nt = 0; nt < 2; ++nt) {
        const int vc = h * 32 + nt * 16 + l15;
        f32x4 o = {0.f, 0.f, 0.f, 0.f};
        #pragma unroll
        for (int ks2 = 0; ks2 < 2; ++ks2) {
          const int tk = (ks2 * 32 + g * 8) ^ ((vc & 7) << 3);
          short8v vf = *reinterpret_cast<const short8v*>(&vts[u][vc][tk]);
          o = __builtin_amdgcn_mfma_f32_16x16x32_bf16(vf, pfv[u][ks2], o, 0, 0, 0);
        }
        oacc[nt] = o;
      }
      // normalize+pack O -> proj A-fragment (proj_wb pre-permuted)
      unsigned o00 = cvtpk(oacc[0][0] * inv[u], oacc[0][1] * inv[u]);
      unsigned o01 = cvtpk(oacc[0][2] * inv[u], oacc[0][3] * inv[u]);
      unsigned o10 = cvtpk(oacc[1][0] * inv[u], oacc[1][1] * inv[u]);
      unsigned o11 = cvtpk(oacc[1][2] * inv[u], oacc[1][3] * inv[u]);
      ofv[h][u] = bits8(o00, o01, o10, o11);
    }
  }

  // output projection (all heads): pacc[u][nt2] = sum_h O_h @ Wp_h
  f32x4 pacc[4][6];
  #pragma unroll
  for (int u = 0; u < 4; ++u)
    #pragma unroll
    for (int nt2 = 0; nt2 < 6; ++nt2) pacc[u][nt2] = (f32x4){0.f, 0.f, 0.f, 0.f};
  #pragma unroll
  for (int h = 0; h < 3; ++h) {
    #pragma unroll
    for (int nt2 = 0; nt2 < 6; ++nt2) {
      short8v pfw = *reinterpret_cast<const short8v*>(proj_wb + (nt2 * 16 + l15) * 96 + h * 32 + g * 8);
      #pragma unroll
      for (int u = 0; u < 4; ++u)
        pacc[u][nt2] = __builtin_amdgcn_mfma_f32_16x16x32_bf16(ofv[h][u], pfw, pacc[u][nt2], 0, 0, 0);
    }
  }

  // epilogue: + proj bias, f32 stores for all four windows
  float pb[6];
  #pragma unroll
  for (int nt2 = 0; nt2 < 6; ++nt2) pb[nt2] = proj_b[nt2 * 16 + l15];
  #pragma unroll
  for (int u = 0; u < 4; ++u) {
    const int win = bb + ((u >> 1) << 11) + ((u & 1) << 12);
    float* ob = out + (size_t)win * 6144 + (w * 16 + g * 4) * 96 + l15;
    #pragma unroll
    for (int nt2 = 0; nt2 < 6; ++nt2)
      #pragma unroll
      for (int r = 0; r < 4; ++r)
        ob[r * 96 + nt2 * 16] = pacc[u][nt2][r] + pb[nt2];
  }
}

extern "C" void kernel_launch(void* const* d_in, const int* in_sizes, int n_in,
                              void* d_out, int out_size, void* d_ws, size_t ws_size,
                              hipStream_t stream) {
  const float* x          = (const float*)d_in[0];
  const float* mask       = (const float*)d_in[1];
  const float* qkv_w      = (const float*)d_in[2];
  const float* qkv_b      = (const float*)d_in[3];
  const float* proj_w     = (const float*)d_in[4];
  const float* proj_b     = (const float*)d_in[5];
  const float* bias_table = (const float*)d_in[6];
  const int*   rel_idx    = (const int*)d_in[7];

  char* ws = (char*)d_ws;
  ushort* qkv_wb    = (ushort*)ws;                    // 288*96*2 = 55296 B
  ushort* proj_wb   = (ushort*)(ws + 55296);          // 96*96*2  = 18432 B
  float*  bias_comb = (float*)(ws + 55296 + 18432);   // 3*64*64*4 = 49152 B
  float*  qkv_bs    = (float*)(ws + 55296 + 18432 + 49152);  // 288*4 = 1152 B

  setup_k<<<194, 256, 0, stream>>>(qkv_w, proj_w, bias_table, rel_idx, qkv_b,
                                   qkv_wb, proj_wb, bias_comb, qkv_bs);
  winattn<<<2048, 256, 0, stream>>>(x, mask, qkv_wb, proj_wb,
                                    bias_comb, qkv_bs, proj_b, (float*)d_out);
}